// Round 8
// baseline (274.936 us; speedup 1.0000x reference)
//
#include <hip/hip_runtime.h>
#include <hip/hip_bf16.h>
#include <math.h>

#define DEV __device__ __forceinline__

typedef short bf16x8 __attribute__((ext_vector_type(8)));
typedef short bf16x4 __attribute__((ext_vector_type(4)));
typedef float f32x4 __attribute__((ext_vector_type(4)));

static constexpr int D  = 1024;
static constexpr int H  = 16;
static constexpr int HD = 64;
static constexpr int DS = 64;
static constexpr int B  = 2;
static constexpr int L  = 2048;
static constexpr int M  = B * L;   // 4096

// softmax scale * log2(e), folded into q at projection time (exp2-based
// softmax, no max subtraction: scores bounded far below exp2 overflow;
// masked scores (-1e30) give exp2 -> 0 exactly).
static constexpr float QSCALE = 0.18033688011112042f; // 0.125 * log2(e)

DEV unsigned short f2bf(float f) {
  union { float f; unsigned u; } x; x.f = f;
  unsigned r = (x.u + 0x7FFFu + ((x.u >> 16) & 1u)) >> 16;
  return (unsigned short)r;
}

DEV unsigned pack2bf(float a, float b) {
  return (unsigned)f2bf(a) | ((unsigned)f2bf(b) << 16);
}

// truncation pack (P only: truncation bias cancels between Sum(p*v) and Sum(p))
// single v_perm_b32: bytes [ua.b2, ua.b3, ub.b2, ub.b3]
DEV unsigned pack2bf_trunc(float a, float b) {
  union { float f; unsigned u; } ua{a}, ub{b};
  return __builtin_amdgcn_perm(ub.u, ua.u, 0x07060302u);
}

// async global->LDS, 16B per lane; LDS dest = wave-uniform base + 16*lane.
DEV void gload_lds16(const void* g, void* l) {
  __builtin_amdgcn_global_load_lds(
      (const __attribute__((address_space(1))) unsigned int*)g,
      (__attribute__((address_space(3))) unsigned int*)l, 16, 0, 0);
}

// ---------------- merged preprocessing ----------------
// blocks [0,1024): W transpose+bf16; [1024,3072): x->bf16; [3072,3088): sq/sk
__global__ __launch_bounds__(256) void prep_kernel(
    const float* __restrict__ Wq, const float* __restrict__ Wk,
    const float* __restrict__ Wv, const float* __restrict__ Wo,
    const float* __restrict__ x, const float* __restrict__ subj,
    const float* __restrict__ Wsq, const float* __restrict__ bsq,
    const float* __restrict__ Wsk, const float* __restrict__ bsk,
    unsigned short* __restrict__ WT4, unsigned short* __restrict__ xb,
    float* __restrict__ sq, float* __restrict__ sk) {
  __shared__ float tile[64][65];
  const int blk = blockIdx.x, t = threadIdx.x;
  if (blk < 1024) {
    const int z = blk >> 8, idx = blk & 255;
    const float* W = z == 0 ? Wq : z == 1 ? Wk : z == 2 ? Wv : Wo;
    unsigned short* dst = WT4 + (size_t)z * D * D;
    const int n0 = (idx & 15) * 64, k0 = (idx >> 4) * 64;
    const int c = t & 63, r4 = t >> 6;
#pragma unroll
    for (int rr = 0; rr < 16; ++rr) {
      int row = r4 + rr * 4;
      tile[row][c] = W[(size_t)(k0 + row) * D + n0 + c];
    }
    __syncthreads();
#pragma unroll
    for (int rr = 0; rr < 16; ++rr) {
      int nrow = r4 + rr * 4;
      dst[(size_t)(n0 + nrow) * D + k0 + c] = f2bf(tile[c][nrow]);
    }
  } else if (blk < 3072) {
    size_t g = (size_t)(blk - 1024) * 256 + t;
    const float4* xf = (const float4*)x;
    float4 a = xf[2 * g], b = xf[2 * g + 1];
    union { unsigned short s[8]; uint4 v; } o;
    o.s[0] = f2bf(a.x); o.s[1] = f2bf(a.y); o.s[2] = f2bf(a.z); o.s[3] = f2bf(a.w);
    o.s[4] = f2bf(b.x); o.s[5] = f2bf(b.y); o.s[6] = f2bf(b.z); o.s[7] = f2bf(b.w);
    ((uint4*)xb)[g] = o.v;
  } else {
    int g = (blk - 3072) * 256 + t;  // [0, 4096)
    int ty = g >> 11, b = (g >> 10) & 1, n = g & 1023;
    const float* W = ty ? Wsk : Wsq;
    const float* bias = ty ? bsk : bsq;
    float s = bias[n];
#pragma unroll 8
    for (int d = 0; d < DS; ++d) s += subj[b * DS + d] * W[d * D + n];
    (ty ? sk : sq)[b * D + n] = s;
  }
}

// ---------------- fused QKV projection GEMM (BK=64, reg-staged) ---------
// z=0: q = (x@Wq + sq)*QSCALE -> qk[0]; z=1: k = x@Wk + sk -> qk[1]
// z=2: v = x@Wv written directly transposed to vT[B,H,64,L] (fused vtrans).
// XCD-chunked block swizzle (bijective: 768 = 8 XCDs x 96) keeps xb/W
// re-reads in the XCD-local L2 (FETCH 68.7 -> 29.8 MB, measured r4).
// Register-staged 2-phase (T14): issue next K-tile's 8x global_load_dwordx4
// into VGPRs BEFORE the MFMA block; ds_write_b128 after the read-barrier.
// LDS stays 34.8 KB -> 3 grid-blocks/CU co-resident (12 waves/CU).
// __launch_bounds__(256, 3): VGPR cap 512/3=170 >= the ~155 live peak
// (acc 64 + ra/rb 32 + af/bf 32 + addr). r7 measured: without this the
// compiler allocated 96 VGPR and spilled ra/rb to scratch every K-step
// (WRITE_SIZE 24.6 -> 205 MB, proj 43 -> 128 us). The cap forbids that.
__global__ __launch_bounds__(256, 3) void proj_kernel(
    const unsigned short* __restrict__ xb, const unsigned short* __restrict__ WT3,
    const float* __restrict__ sq, const float* __restrict__ sk,
    unsigned short* __restrict__ qk, unsigned short* __restrict__ vT) {
  __shared__ __align__(16) unsigned short smem[128 * 136];  // 34.8 KB
  unsigned short* As = smem;             // 128*64 (16 KB)
  unsigned short* Bs = smem + 128 * 64;  // 128*64 (16 KB)
  const int lin = blockIdx.x + 8 * (blockIdx.y + 32 * blockIdx.z);
  const int nlin = (lin & 7) * 96 + (lin >> 3);   // XCD chunk remap
  const int z = nlin >> 8;
  const int rem = nlin & 255;
  const unsigned short* Wt = WT3 + (size_t)z * D * D;
  const int m0 = (rem >> 3) * 128, n0 = (rem & 7) * 128;
  const int t = threadIdx.x, l = t & 63, w = t >> 6;
  const int wm = w >> 1, wn = w & 1;
  const int lm = l & 15, lq = l >> 4;
  const int srow8 = t >> 3;
  const int fsw = ((t & 7) ^ ((t >> 3) & 7)) * 8;
  const int swm = lm & 7;

  uint4 ra[4], rb[4];
  auto issue = [&](int kt) {
    const int kb = kt * 64;
#pragma unroll
    for (int c = 0; c < 4; ++c) {
      ra[c] = *(const uint4*)&xb[(size_t)(m0 + 32 * c + srow8) * D + kb + fsw];
      rb[c] = *(const uint4*)&Wt[(size_t)(n0 + 32 * c + srow8) * D + kb + fsw];
    }
  };
  auto commit = [&]() {
#pragma unroll
    for (int c = 0; c < 4; ++c) {
      *(uint4*)&As[(32 * c + 8 * w) * 64 + l * 8] = ra[c];
      *(uint4*)&Bs[(32 * c + 8 * w) * 64 + l * 8] = rb[c];
    }
  };

  f32x4 acc[4][4] = {};
  issue(0);
  commit();
  __syncthreads();
  for (int kt = 0; kt < D / 64; ++kt) {
    if (kt + 1 < D / 64) issue(kt + 1);
#pragma unroll
    for (int kk = 0; kk < 2; ++kk) {
      bf16x8 af[4], bf[4];
#pragma unroll
      for (int i = 0; i < 4; ++i)
        af[i] = *(const bf16x8*)&As[(64 * wm + 16 * i + lm) * 64 + ((kk * 4 + lq) ^ swm) * 8];
#pragma unroll
      for (int j = 0; j < 4; ++j)
        bf[j] = *(const bf16x8*)&Bs[(64 * wn + 16 * j + lm) * 64 + ((kk * 4 + lq) ^ swm) * 8];
#pragma unroll
      for (int i = 0; i < 4; ++i)
#pragma unroll
        for (int j = 0; j < 4; ++j)
          acc[i][j] = __builtin_amdgcn_mfma_f32_16x16x32_bf16(af[i], bf[j], acc[i][j], 0, 0, 0);
    }
    __syncthreads();                 // all waves done reading As/Bs
    if (kt + 1 < D / 64) {
      commit();                      // vmcnt wait folded here (post-compute)
      __syncthreads();               // LDS ready for next step
    }
  }
  if (z == 2) {
    // transpose epilogue: acc -> smem T[col][row] (stride 136) -> vT
    // (smem pool is dead past the final loop barrier)
#pragma unroll
    for (int i = 0; i < 4; ++i)
#pragma unroll
      for (int j = 0; j < 4; ++j) {
        int cr = 64 * wn + 16 * j + lm;
        int rr = 64 * wm + 16 * i + 4 * lq;
        uint2 u;
        u.x = pack2bf(acc[i][j][0], acc[i][j][1]);
        u.y = pack2bf(acc[i][j][2], acc[i][j][3]);
        *(uint2*)&smem[cr * 136 + rr] = u;
      }
    __syncthreads();
    const int cr = t >> 1, half = t & 1;
    const int bb = m0 >> 11, l0 = m0 & (L - 1);
    const int gcol = n0 + cr, h = gcol >> 6, hd = gcol & 63;
    size_t dbase = ((size_t)(bb * H + h) * HD + hd) * L + l0 + half * 64;
#pragma unroll
    for (int c = 0; c < 8; ++c) {
      uint4 u = *(const uint4*)&smem[cr * 136 + half * 64 + c * 8];
      *(uint4*)&vT[dbase + c * 8] = u;
    }
  } else {
    unsigned short* dst = qk + (size_t)z * M * D;
    const float* bias = z == 0 ? sq : sk;
    const float post = z == 0 ? QSCALE : 1.0f;
    // stage [row][col] into smem, then fully-coalesced 16B stores
#pragma unroll
    for (int i = 0; i < 4; ++i)
#pragma unroll
      for (int j = 0; j < 4; ++j)
#pragma unroll
        for (int r = 0; r < 4; ++r) {
          int rr = 64 * wm + 16 * i + 4 * lq + r;
          int cc = 64 * wn + 16 * j + lm;
          float v = (acc[i][j][r] + bias[((m0 + rr) >> 11) * D + n0 + cc]) * post;
          smem[rr * 136 + cc] = f2bf(v);
        }
    __syncthreads();
    const int row = t >> 1, half = t & 1;
    const int bb = m0 >> 11, ll = (m0 & (L - 1)) + row;
    const int h0 = (n0 >> 6) + half;
    size_t dbase = ((size_t)(bb * H + h0) * L + ll) * HD;
#pragma unroll
    for (int c = 0; c < 8; ++c) {
      uint4 u = *(const uint4*)&smem[row * 136 + half * 64 + c * 8];
      *(uint4*)&dst[dbase + c * 8] = u;
    }
  }
}

// ---------------- flash attention (BK=128, register P, dbuf) ----------
// grid 512 XCD-swizzled; block 512 = 8 waves. Wave-pair key-split:
// wave w owns q-rows 32*(w&3)..+31 and 64 keys (2 groups of 32) of each
// 128-key tile. PV uses full-width mfma_f32_16x16x32_bf16 over 32-key
// groups via the QK^T A-operand K-row REMAP (see krow0/krow1).
// Row-sums are computed by an extra ones-column MFMA per group
// (mfma(pa, ones, ot1)): per-lane C-layout sums of the SAME truncated
// bf16 p-values used in PV (truncation bias cancels exactly in the ratio),
// eliminating the scalar adds + all epilogue shuffles.
// s_setprio(1) wraps the MFMA clusters (T5).
// Mask bytes are loaded BEFORE the prefetch DMAs so the ballot's vmcnt wait
// does not drain the prefetch (FIFO vmcnt: mask loads are the oldest).
__global__ __launch_bounds__(512, 4) void attn_kernel(
    const unsigned short* __restrict__ q_hm, const unsigned short* __restrict__ k_hm,
    const unsigned short* __restrict__ vT, const unsigned char* __restrict__ mask,
    unsigned short* __restrict__ ctx) {
  __shared__ __align__(16) unsigned short smem[40960];  // 80 KB pool
  unsigned short* Qs  = smem;                // 128*64   (16 KB)
  unsigned short* Ksb = smem + 8192;         // 2*128*64 (32 KB) [buf][key][feat]
  unsigned short* Vtb = smem + 24576;        // 2*64*128 (32 KB) [buf][feat][key]
  const int bx = blockIdx.x;
  const int rest = bx >> 3;
  const int bhid = (bx & 7) + 8 * (rest >> 4);
  const int q0 = (rest & 15) * 128;
  const int h = bhid & 15, b = bhid >> 4;
  const size_t bh = (size_t)(b * H + h);
  const unsigned short* qp = q_hm + bh * L * HD;
  const unsigned short* kp = k_hm + bh * L * HD;
  const unsigned short* vp = vT + bh * HD * L;
  const int t = threadIdx.x, l = t & 63, w = t >> 6;
  const int wq = w & 3, wj = w >> 2;               // q-row group, key half
  const int lm = l & 15, lq = l >> 4;
  const int fsw = ((t & 7) ^ ((t >> 3) & 7)) * 8;  // 8-chunk swizzle (64-wide rows)
  const int swm = lm & 7;
  const int srow = t >> 3;                         // 0..63
  const int vs = t & 15, vr = t >> 4;              // V staging: slot, row (0..31)
  const int vcsrc = ((vs & 8) | ((vs & 7) ^ (vr & 7))) * 8;  // 16-chunk swizzle
  // K=32 A-layout key-row remap (see header comment)
  const int krow0 = 8 * (lm >> 2) + 4 * ((lm >> 2) & 1) + (lm & 3);
  const int ks0 = krow0 & 7;
  const int krow1 = krow0 ^ 4;
  const int ks1 = ks0 ^ 4;
  const bf16x8 vones = {(short)0x3F80, (short)0x3F80, (short)0x3F80, (short)0x3F80,
                        (short)0x3F80, (short)0x3F80, (short)0x3F80, (short)0x3F80};

  // stage Q + first K/V tile (512 threads: 2 rounds each)
#pragma unroll
  for (int c = 0; c < 2; ++c) {
    gload_lds16(&qp[(size_t)(q0 + 64 * c + srow) * HD + fsw], &Qs[(64 * c + 8 * w) * 64]);
    gload_lds16(&kp[(size_t)(64 * c + srow) * HD + fsw], &Ksb[(64 * c + 8 * w) * 64]);
    gload_lds16(&vp[(size_t)(32 * c + vr) * L + vcsrc], &Vtb[(32 * c + 4 * w) * 128]);
  }
  __syncthreads();
  bf16x8 qf[2][2];
#pragma unroll
  for (int i = 0; i < 2; ++i)
#pragma unroll
    for (int kk = 0; kk < 2; ++kk)
      qf[i][kk] = *(const bf16x8*)&Qs[(wq * 32 + 16 * i + lm) * 64 + ((kk * 4 + lq) ^ swm) * 8];

  f32x4 ot[2][4] = {};   // O[qrow=32wq+16i+4lq+r][feat=16jf+lm], this wave's key-half
  f32x4 ot1[2] = {};     // row-sums (ones-column): lane rows 4lq+r (lm duplicated)

  for (int kt = 0; kt < L / 128; ++kt) {
    const int cur = kt & 1;
    const unsigned short* Kc = Ksb + cur * 8192;
    const unsigned short* Vc = Vtb + cur * 8192;
    // mask bytes FIRST (oldest vmcnt entries); each wave needs only its half
    unsigned char mby = mask[b * L + kt * 128 + 64 * wj + l];
    if (kt + 1 < L / 128) {
      const int nk0 = (kt + 1) * 128;
      unsigned short* Kd = Ksb + (cur ^ 1) * 8192;
      unsigned short* Vd = Vtb + (cur ^ 1) * 8192;
#pragma unroll
      for (int c = 0; c < 2; ++c) {
        gload_lds16(&kp[(size_t)(nk0 + 64 * c + srow) * HD + fsw], &Kd[(64 * c + 8 * w) * 64]);
        gload_lds16(&vp[(size_t)(32 * c + vr) * L + nk0 + vcsrc], &Vd[(32 * c + 4 * w) * 128]);
      }
    }
    unsigned long long mb = __ballot(mby != 0);

#pragma unroll
    for (int g = 0; g < 2; ++g) {
      const int gg = 2 * wj + g;            // 32-key group within 128-key tile
      const unsigned short* Kg = Kc + 32 * gg * 64;
      // remapped K fragments: rows krow0 (->j per lq parity) and krow1
      bf16x8 ka0 = *(const bf16x8*)&Kg[krow0 * 64 + ((0 + lq) ^ ks0) * 8];
      bf16x8 ka1 = *(const bf16x8*)&Kg[krow0 * 64 + ((4 + lq) ^ ks0) * 8];
      bf16x8 kb0 = *(const bf16x8*)&Kg[krow1 * 64 + ((0 + lq) ^ ks1) * 8];
      bf16x8 kb1 = *(const bf16x8*)&Kg[krow1 * 64 + ((4 + lq) ^ ks1) * 8];
      f32x4 stA[2], stB[2];
      __builtin_amdgcn_s_setprio(1);
#pragma unroll
      for (int i = 0; i < 2; ++i) {
        f32x4 a = {};
        a = __builtin_amdgcn_mfma_f32_16x16x32_bf16(ka0, qf[i][0], a, 0, 0, 0);
        a = __builtin_amdgcn_mfma_f32_16x16x32_bf16(ka1, qf[i][1], a, 0, 0, 0);
        stA[i] = a;
        f32x4 bq = {};
        bq = __builtin_amdgcn_mfma_f32_16x16x32_bf16(kb0, qf[i][0], bq, 0, 0, 0);
        bq = __builtin_amdgcn_mfma_f32_16x16x32_bf16(kb1, qf[i][1], bq, 0, 0, 0);
        stB[i] = bq;
      }
      __builtin_amdgcn_s_setprio(0);
      if (mb) {  // wave-uniform; all-false mask skips this
        // stA lane keys: 32g + 8lq + 4(lq&1) + r; stB: ^4
        const int shA = 32 * g + 8 * lq + 4 * (lq & 1);
        unsigned bitsA = (unsigned)(mb >> shA);
        unsigned bitsB = (unsigned)(mb >> (shA ^ 4));
#pragma unroll
        for (int i = 0; i < 2; ++i)
#pragma unroll
          for (int r = 0; r < 4; ++r) {
            if ((bitsA >> r) & 1u) stA[i][r] = -1e30f;
            if ((bitsB >> r) & 1u) stB[i][r] = -1e30f;
          }
      }
      // p = exp2(s); build K=32 A-fragment (lq parity selects quad order)
      union { uint4 q; bf16x8 v; } pa[2];
      const bool sw = (lq & 1) != 0;
#pragma unroll
      for (int i = 0; i < 2; ++i) {
        float eA[4], eB[4];
#pragma unroll
        for (int r = 0; r < 4; ++r) {
          eA[r] = __builtin_amdgcn_exp2f(stA[i][r]);
          eB[r] = __builtin_amdgcn_exp2f(stB[i][r]);
        }
        unsigned a01 = pack2bf_trunc(eA[0], eA[1]);
        unsigned a23 = pack2bf_trunc(eA[2], eA[3]);
        unsigned b01 = pack2bf_trunc(eB[0], eB[1]);
        unsigned b23 = pack2bf_trunc(eB[2], eB[3]);
        pa[i].q.x = sw ? b01 : a01;
        pa[i].q.y = sw ? b23 : a23;
        pa[i].q.z = sw ? a01 : b01;
        pa[i].q.w = sw ? a23 : b23;
      }
      // O += P@V for this 32-key group (b128 V^T reads, K=32 MFMA);
      // ones-column MFMA accumulates row-sums into ot1 (C-layout rows).
      const int kc = 4 * gg + lq;                    // 8-key chunk index
      const int slot = (kc & 8) | ((kc & 7) ^ swm);
      __builtin_amdgcn_s_setprio(1);
#pragma unroll
      for (int jf = 0; jf < 4; ++jf) {
        bf16x8 vb = *(const bf16x8*)&Vc[(16 * jf + lm) * 128 + slot * 8];
#pragma unroll
        for (int i = 0; i < 2; ++i)
          ot[i][jf] = __builtin_amdgcn_mfma_f32_16x16x32_bf16(pa[i].v, vb, ot[i][jf], 0, 0, 0);
      }
#pragma unroll
      for (int i = 0; i < 2; ++i)
        ot1[i] = __builtin_amdgcn_mfma_f32_16x16x32_bf16(pa[i].v, vones, ot1[i], 0, 0, 0);
      __builtin_amdgcn_s_setprio(0);
    }
    __syncthreads();
  }

  // ---- epilogue: combine wave-pair partials, normalize, store ----
  // All K/V/Q LDS is dead past the final loop barrier; carve scratch:
  float* Obuf = (float*)smem;                 // [64 cols][stride 132] f32, 33.8 KB
  unsigned short* Es = smem + 20480;          // byte 40960; stride-72 rows, 18.4 KB
  float* Sred = (float*)(smem + 35840);       // byte 71680; 8*32 floats

  // publish C-layout row sums (rows 32wq+16i+4lq+r); lm lanes duplicate
  if (lm == 0) {
#pragma unroll
    for (int i = 0; i < 2; ++i)
#pragma unroll
      for (int r = 0; r < 4; ++r)
        Sred[w * 32 + 16 * i + 4 * lq + r] = ot1[i][r];
  }
  if (wj) {
    // upper waves park raw O partials (col-major, r contiguous -> f32x4)
#pragma unroll
    for (int i = 0; i < 2; ++i)
#pragma unroll
      for (int jf = 0; jf < 4; ++jf)
        *(f32x4*)&Obuf[(16 * jf + lm) * 132 + wq * 32 + 16 * i + 4 * lq] = ot[i][jf];
  }
  __syncthreads();
  if (!wj) {
    float rlq[2][4];
#pragma unroll
    for (int i = 0; i < 2; ++i)
#pragma unroll
      for (int r = 0; r < 4; ++r)
        rlq[i][r] = 1.0f / (ot1[i][r] + Sred[(w + 4) * 32 + 16 * i + 4 * lq + r]);
#pragma unroll
    for (int i = 0; i < 2; ++i)
#pragma unroll
      for (int jf = 0; jf < 4; ++jf) {
        f32x4 po = *(const f32x4*)&Obuf[(16 * jf + lm) * 132 + wq * 32 + 16 * i + 4 * lq];
        ot[i][jf] += po;
      }
    // O rows -> Es (stride 72) -> coalesced 16B stores.
    // Safe without barrier: each wave touches only its own 32 rows.
#pragma unroll
    for (int i = 0; i < 2; ++i)
#pragma unroll
      for (int jf = 0; jf < 4; ++jf)
#pragma unroll
        for (int r = 0; r < 4; ++r)
          Es[(wq * 32 + 16 * i + 4 * lq + r) * 72 + 16 * jf + lm] =
              f2bf(ot[i][jf][r] * rlq[i][r]);
    int row = l >> 1, half = l & 1;
    size_t obase = ((size_t)(b * L + q0 + wq * 32 + row)) * D + h * HD + half * 32;
#pragma unroll
    for (int c = 0; c < 4; ++c) {
      uint4 u = *(const uint4*)&Es[(wq * 32 + row) * 72 + half * 32 + c * 8];
      *(uint4*)&ctx[obase + c * 8] = u;
    }
  }
}

// ---------------- output projection GEMM (BK=64, 2-phase dbuf) ----------
// out = ctx@Wo + bo. XCD-chunked block swizzle (bijective: 512 = 8 x 64)
// + 2-phase gload_lds prefetch (grid 512 = exactly 2 blocks/CU: no
// residency loss from the 48 KB LDS, unlike proj's 768-grid case).
__global__ __launch_bounds__(256) void outgemm_kernel(
    const unsigned short* __restrict__ ctx, const unsigned short* __restrict__ WoT,
    const float* __restrict__ bo, float* __restrict__ out) {
  __shared__ __align__(16) unsigned short smem[24576];  // 48 KB: 2x(As+Bs)
  const int lin = blockIdx.x + 8 * blockIdx.y;
  const int nlin = (lin & 7) * 64 + (lin >> 3);   // XCD chunk remap
  const int m0 = (nlin >> 3) * 64, n0 = (nlin & 7) * 128;
  const int t = threadIdx.x, l = t & 63, w = t >> 6;
  const int wm = w >> 1, wn = w & 1;
  const int lm = l & 15, lq = l >> 4;
  const int srow8 = t >> 3;
  const int fsw = ((t & 7) ^ ((t >> 3) & 7)) * 8;
  const int swm = lm & 7;

  auto stage = [&](int kt, int bsel) {
    const int kb = kt * 64;
    unsigned short* As = smem + bsel * 12288;
    unsigned short* Bs = As + 4096;
#pragma unroll
    for (int c = 0; c < 2; ++c)
      gload_lds16(&ctx[(size_t)(m0 + 32 * c + srow8) * D + kb + fsw],
                  &As[(32 * c + 8 * w) * 64]);
#pragma unroll
    for (int c = 0; c < 4; ++c)
      gload_lds16(&WoT[(size_t)(n0 + 32 * c + srow8) * D + kb + fsw],
                  &Bs[(32 * c + 8 * w) * 64]);
  };

  f32x4 acc[2][4] = {};
  stage(0, 0);
  __syncthreads();
  for (int kt = 0; kt < D / 64; ++kt) {
    const int cur = kt & 1;
    if (kt + 1 < D / 64) stage(kt + 1, cur ^ 1);
    const unsigned short* As = smem + cur * 12288;
    const unsigned short* Bs = As + 4096;
#pragma unroll
    for (int kk = 0; kk < 2; ++kk) {
      bf16x8 af[2], bf[4];
#pragma unroll
      for (int i = 0; i < 2; ++i)
        af[i] = *(const bf16x8*)&As[(32 * wm + 16 * i + lm) * 64 + ((kk * 4 + lq) ^ swm) * 8];
#pragma unroll
      for (int j = 0; j < 4; ++j)
        bf[j] = *(const bf16x8*)&Bs[(64 * wn + 16 * j + lm) * 64 + ((kk * 4 + lq) ^ swm) * 8];
#pragma unroll
      for (int i = 0; i < 2; ++i)
#pragma unroll
        for (int j = 0; j < 4; ++j)
          acc[i][j] = __builtin_amdgcn_mfma_f32_16x16x32_bf16(af[i], bf[j], acc[i][j], 0, 0, 0);
    }
    __syncthreads();
  }
#pragma unroll
  for (int i = 0; i < 2; ++i)
#pragma unroll
    for (int j = 0; j < 4; ++j)
#pragma unroll
      for (int r = 0; r < 4; ++r) {
        int grow = m0 + 32 * wm + 16 * i + lq * 4 + r;
        int gcol = n0 + 64 * wn + 16 * j + lm;
        out[(size_t)grow * D + gcol] = acc[i][j][r] + bo[gcol];
      }
}

extern "C" void kernel_launch(void* const* d_in, const int* in_sizes, int n_in,
                              void* d_out, int out_size, void* d_ws, size_t ws_size,
                              hipStream_t stream) {
  const float* x    = (const float*)d_in[0];
  const float* subj = (const float*)d_in[1];
  const unsigned char* mask = (const unsigned char*)d_in[2];
  const float* Wq = (const float*)d_in[3];
  const float* Wk = (const float*)d_in[4];
  const float* Wv = (const float*)d_in[5];
  const float* Wo = (const float*)d_in[6];
  const float* bo = (const float*)d_in[7];
  const float* Wsq = (const float*)d_in[8];
  const float* bsq = (const float*)d_in[9];
  const float* Wsk = (const float*)d_in[10];
  const float* bsk = (const float*)d_in[11];
  float* out = (float*)d_out;
  char* ws = (char*)d_ws;

  // workspace layout (bytes)
  unsigned short* xb  = (unsigned short*)(ws);                    // 8 MB
  unsigned short* WT4 = (unsigned short*)(ws + (8ull  << 20));    // 8 MB
  unsigned short* qk  = (unsigned short*)(ws + (16ull << 20));    // 16 MB (q,k)
  unsigned short* ctx = (unsigned short*)(ws + (32ull << 20));    // 8 MB
  unsigned short* vT  = (unsigned short*)(ws + (40ull << 20));    // 8 MB
  float* sq = (float*)(ws + (48ull << 20));                       // 8 KB
  float* sk = sq + B * D;

  hipLaunchKernelGGL(prep_kernel, dim3(3088), dim3(256), 0, stream,
                     Wq, Wk, Wv, Wo, x, subj, Wsq, bsq, Wsk, bsk, WT4, xb, sq, sk);
  hipLaunchKernelGGL(proj_kernel, dim3(8, 32, 3), dim3(256), 0, stream,
                     xb, WT4, sq, sk, qk, vT);
  hipLaunchKernelGGL(attn_kernel, dim3(512), dim3(512), 0, stream,
                     qk, qk + (size_t)M * D, vT, mask, ctx);
  hipLaunchKernelGGL(outgemm_kernel, dim3(8, 64, 1), dim3(256), 0, stream, ctx,
                     WT4 + 3ull * D * D, bo, out);
}

// Round 11
// 198.802 us; speedup vs baseline: 1.3830x; 1.3830x over previous
//
#include <hip/hip_runtime.h>
#include <hip/hip_bf16.h>
#include <math.h>

#define DEV __device__ __forceinline__

typedef short bf16x8 __attribute__((ext_vector_type(8)));
typedef short bf16x4 __attribute__((ext_vector_type(4)));
typedef float f32x4 __attribute__((ext_vector_type(4)));

static constexpr int D  = 1024;
static constexpr int H  = 16;
static constexpr int HD = 64;
static constexpr int DS = 64;
static constexpr int B  = 2;
static constexpr int L  = 2048;
static constexpr int M  = B * L;   // 4096

// softmax scale * log2(e), folded into q at projection time (exp2-based
// softmax, no max subtraction: scores bounded far below exp2 overflow;
// masked scores (-1e30) give exp2 -> 0 exactly).
static constexpr float QSCALE = 0.18033688011112042f; // 0.125 * log2(e)

DEV unsigned short f2bf(float f) {
  union { float f; unsigned u; } x; x.f = f;
  unsigned r = (x.u + 0x7FFFu + ((x.u >> 16) & 1u)) >> 16;
  return (unsigned short)r;
}

DEV unsigned pack2bf(float a, float b) {
  return (unsigned)f2bf(a) | ((unsigned)f2bf(b) << 16);
}

// truncation pack (P only: truncation bias cancels between Sum(p*v) and Sum(p))
// single v_perm_b32: bytes [ua.b2, ua.b3, ub.b2, ub.b3]
DEV unsigned pack2bf_trunc(float a, float b) {
  union { float f; unsigned u; } ua{a}, ub{b};
  return __builtin_amdgcn_perm(ub.u, ua.u, 0x07060302u);
}

// async global->LDS, 16B per lane; LDS dest = wave-uniform base + 16*lane.
DEV void gload_lds16(const void* g, void* l) {
  __builtin_amdgcn_global_load_lds(
      (const __attribute__((address_space(1))) unsigned int*)g,
      (__attribute__((address_space(3))) unsigned int*)l, 16, 0, 0);
}

// ---------------- merged preprocessing ----------------
// blocks [0,1024): W transpose+bf16; [1024,3072): x->bf16; [3072,3088): sq/sk
__global__ __launch_bounds__(256) void prep_kernel(
    const float* __restrict__ Wq, const float* __restrict__ Wk,
    const float* __restrict__ Wv, const float* __restrict__ Wo,
    const float* __restrict__ x, const float* __restrict__ subj,
    const float* __restrict__ Wsq, const float* __restrict__ bsq,
    const float* __restrict__ Wsk, const float* __restrict__ bsk,
    unsigned short* __restrict__ WT4, unsigned short* __restrict__ xb,
    float* __restrict__ sq, float* __restrict__ sk) {
  __shared__ float tile[64][65];
  const int blk = blockIdx.x, t = threadIdx.x;
  if (blk < 1024) {
    const int z = blk >> 8, idx = blk & 255;
    const float* W = z == 0 ? Wq : z == 1 ? Wk : z == 2 ? Wv : Wo;
    unsigned short* dst = WT4 + (size_t)z * D * D;
    const int n0 = (idx & 15) * 64, k0 = (idx >> 4) * 64;
    const int c = t & 63, r4 = t >> 6;
#pragma unroll
    for (int rr = 0; rr < 16; ++rr) {
      int row = r4 + rr * 4;
      tile[row][c] = W[(size_t)(k0 + row) * D + n0 + c];
    }
    __syncthreads();
#pragma unroll
    for (int rr = 0; rr < 16; ++rr) {
      int nrow = r4 + rr * 4;
      dst[(size_t)(n0 + nrow) * D + k0 + c] = f2bf(tile[c][nrow]);
    }
  } else if (blk < 3072) {
    size_t g = (size_t)(blk - 1024) * 256 + t;
    const float4* xf = (const float4*)x;
    float4 a = xf[2 * g], b = xf[2 * g + 1];
    union { unsigned short s[8]; uint4 v; } o;
    o.s[0] = f2bf(a.x); o.s[1] = f2bf(a.y); o.s[2] = f2bf(a.z); o.s[3] = f2bf(a.w);
    o.s[4] = f2bf(b.x); o.s[5] = f2bf(b.y); o.s[6] = f2bf(b.z); o.s[7] = f2bf(b.w);
    ((uint4*)xb)[g] = o.v;
  } else {
    int g = (blk - 3072) * 256 + t;  // [0, 4096)
    int ty = g >> 11, b = (g >> 10) & 1, n = g & 1023;
    const float* W = ty ? Wsk : Wsq;
    const float* bias = ty ? bsk : bsq;
    float s = bias[n];
#pragma unroll 8
    for (int d = 0; d < DS; ++d) s += subj[b * DS + d] * W[d * D + n];
    (ty ? sk : sq)[b * D + n] = s;
  }
}

// ---------------- fused QKV projection GEMM (BK=32, gload_lds dbuf) -----
// z=0: q = (x@Wq + sq)*QSCALE -> qk[0]; z=1: k = x@Wk + sk -> qk[1]
// z=2: v = x@Wv written directly transposed to vT[B,H,64,L] (fused vtrans).
// XCD-chunked block swizzle (bijective: 768 = 8 XCDs x 96) keeps xb/W
// re-reads in the XCD-local L2 (FETCH 68.7 -> 29.8 MB, measured r4).
// BK=32 double-buffered global_load_lds: staged dbuf = 32 KB inside the
// 34.8 KB pool -> 3 blocks/CU co-resident (grid = exactly 3/CU, 12
// waves/CU). r5's BK=64 dbuf was 64 KB -> 2 blocks/CU and a serialized
// third round (43 us ~= 1.5 x 29). Reg-staging alternatives spilled
// (r7: 96 VGPR/205 MB, r8: 68 VGPR/308 MB) -- gload_lds never spills.
// 32-wide-row swizzle: stage source chunk ((t&3)^((t>>3)&3)), read chunk
// lq^((lm>>1)&3): every 8 consecutive lanes cover all 8 bank-window slots.
__global__ __launch_bounds__(256) void proj_kernel(
    const unsigned short* __restrict__ xb, const unsigned short* __restrict__ WT3,
    const float* __restrict__ sq, const float* __restrict__ sk,
    unsigned short* __restrict__ qk, unsigned short* __restrict__ vT) {
  __shared__ __align__(16) unsigned short smem[128 * 136];  // 34.8 KB pool
  // K-loop carve: As dbuf [0,8192), Bs dbuf [8192,16384) (elements)
  const int lin = blockIdx.x + 8 * (blockIdx.y + 32 * blockIdx.z);
  const int nlin = (lin & 7) * 96 + (lin >> 3);   // XCD chunk remap
  const int z = nlin >> 8;
  const int rem = nlin & 255;
  const unsigned short* Wt = WT3 + (size_t)z * D * D;
  const int m0 = (rem >> 3) * 128, n0 = (rem & 7) * 128;
  const int t = threadIdx.x, l = t & 63, w = t >> 6;
  const int wm = w >> 1, wn = w & 1;
  const int lm = l & 15, lq = l >> 4;
  const int srow4 = t >> 2;                        // 0..63
  const int fsw2 = ((t & 3) ^ ((t >> 3) & 3)) * 8; // 4-chunk swizzle (32-wide)
  const int sw2 = (lm >> 1) & 3;

  auto stage = [&](int kt, int bsel) {
    const int kb = kt * 32;
    unsigned short* As = smem + bsel * 4096;
    unsigned short* Bs = smem + 8192 + bsel * 4096;
#pragma unroll
    for (int c = 0; c < 2; ++c) {
      gload_lds16(&xb[(size_t)(m0 + 64 * c + srow4) * D + kb + fsw2],
                  &As[(64 * c + 16 * w) * 32]);
      gload_lds16(&Wt[(size_t)(n0 + 64 * c + srow4) * D + kb + fsw2],
                  &Bs[(64 * c + 16 * w) * 32]);
    }
  };

  f32x4 acc[4][4] = {};
  stage(0, 0);
  __syncthreads();
  for (int kt = 0; kt < D / 32; ++kt) {
    const int cur = kt & 1;
    if (kt + 1 < D / 32) stage(kt + 1, cur ^ 1);
    const unsigned short* As = smem + cur * 4096;
    const unsigned short* Bs = smem + 8192 + cur * 4096;
    bf16x8 af[4], bf[4];
#pragma unroll
    for (int i = 0; i < 4; ++i)
      af[i] = *(const bf16x8*)&As[(64 * wm + 16 * i + lm) * 32 + ((lq ^ sw2) * 8)];
#pragma unroll
    for (int j = 0; j < 4; ++j)
      bf[j] = *(const bf16x8*)&Bs[(64 * wn + 16 * j + lm) * 32 + ((lq ^ sw2) * 8)];
#pragma unroll
    for (int i = 0; i < 4; ++i)
#pragma unroll
      for (int j = 0; j < 4; ++j)
        acc[i][j] = __builtin_amdgcn_mfma_f32_16x16x32_bf16(af[i], bf[j], acc[i][j], 0, 0, 0);
    __syncthreads();  // vmcnt(0): prefetch (issued pre-compute) has landed;
                      // also guards buf cur against next step's stage()
  }
  if (z == 2) {
    // transpose epilogue: acc -> smem T[col][row] (stride 136) -> vT
    // (the whole 34.8 KB pool is dead past the final loop barrier)
#pragma unroll
    for (int i = 0; i < 4; ++i)
#pragma unroll
      for (int j = 0; j < 4; ++j) {
        int cr = 64 * wn + 16 * j + lm;
        int rr = 64 * wm + 16 * i + 4 * lq;
        uint2 u;
        u.x = pack2bf(acc[i][j][0], acc[i][j][1]);
        u.y = pack2bf(acc[i][j][2], acc[i][j][3]);
        *(uint2*)&smem[cr * 136 + rr] = u;
      }
    __syncthreads();
    const int cr = t >> 1, half = t & 1;
    const int bb = m0 >> 11, l0 = m0 & (L - 1);
    const int gcol = n0 + cr, h = gcol >> 6, hd = gcol & 63;
    size_t dbase = ((size_t)(bb * H + h) * HD + hd) * L + l0 + half * 64;
#pragma unroll
    for (int c = 0; c < 8; ++c) {
      uint4 u = *(const uint4*)&smem[cr * 136 + half * 64 + c * 8];
      *(uint4*)&vT[dbase + c * 8] = u;
    }
  } else {
    unsigned short* dst = qk + (size_t)z * M * D;
    const float* bias = z == 0 ? sq : sk;
    const float post = z == 0 ? QSCALE : 1.0f;
    // stage [row][col] into smem, then fully-coalesced 16B stores
#pragma unroll
    for (int i = 0; i < 4; ++i)
#pragma unroll
      for (int j = 0; j < 4; ++j)
#pragma unroll
        for (int r = 0; r < 4; ++r) {
          int rr = 64 * wm + 16 * i + 4 * lq + r;
          int cc = 64 * wn + 16 * j + lm;
          float v = (acc[i][j][r] + bias[((m0 + rr) >> 11) * D + n0 + cc]) * post;
          smem[rr * 136 + cc] = f2bf(v);
        }
    __syncthreads();
    const int row = t >> 1, half = t & 1;
    const int bb = m0 >> 11, ll = (m0 & (L - 1)) + row;
    const int h0 = (n0 >> 6) + half;
    size_t dbase = ((size_t)(bb * H + h0) * L + ll) * HD;
#pragma unroll
    for (int c = 0; c < 8; ++c) {
      uint4 u = *(const uint4*)&smem[row * 136 + half * 64 + c * 8];
      *(uint4*)&dst[dbase + c * 8] = u;
    }
  }
}

// ---------------- flash attention (BK=128, register P, dbuf) ----------
// grid 512 XCD-swizzled; block 512 = 8 waves. Wave-pair key-split:
// wave w owns q-rows 32*(w&3)..+31 and 64 keys (2 groups of 32) of each
// 128-key tile. PV uses full-width mfma_f32_16x16x32_bf16 over 32-key
// groups via the QK^T A-operand K-row REMAP (see krow0/krow1).
// Row-sums are computed by an extra ones-column MFMA per group
// (mfma(pa, ones, ot1)): per-lane C-layout sums of the SAME truncated
// bf16 p-values used in PV (truncation bias cancels exactly in the ratio),
// eliminating the scalar adds + all epilogue shuffles.
// s_setprio(1) wraps the MFMA clusters (T5).
// Mask bytes are loaded BEFORE the prefetch DMAs so the ballot's vmcnt wait
// does not drain the prefetch (FIFO vmcnt: mask loads are the oldest).
__global__ __launch_bounds__(512, 4) void attn_kernel(
    const unsigned short* __restrict__ q_hm, const unsigned short* __restrict__ k_hm,
    const unsigned short* __restrict__ vT, const unsigned char* __restrict__ mask,
    unsigned short* __restrict__ ctx) {
  __shared__ __align__(16) unsigned short smem[40960];  // 80 KB pool
  unsigned short* Qs  = smem;                // 128*64   (16 KB)
  unsigned short* Ksb = smem + 8192;         // 2*128*64 (32 KB) [buf][key][feat]
  unsigned short* Vtb = smem + 24576;        // 2*64*128 (32 KB) [buf][feat][key]
  const int bx = blockIdx.x;
  const int rest = bx >> 3;
  const int bhid = (bx & 7) + 8 * (rest >> 4);
  const int q0 = (rest & 15) * 128;
  const int h = bhid & 15, b = bhid >> 4;
  const size_t bh = (size_t)(b * H + h);
  const unsigned short* qp = q_hm + bh * L * HD;
  const unsigned short* kp = k_hm + bh * L * HD;
  const unsigned short* vp = vT + bh * HD * L;
  const int t = threadIdx.x, l = t & 63, w = t >> 6;
  const int wq = w & 3, wj = w >> 2;               // q-row group, key half
  const int lm = l & 15, lq = l >> 4;
  const int fsw = ((t & 7) ^ ((t >> 3) & 7)) * 8;  // 8-chunk swizzle (64-wide rows)
  const int swm = lm & 7;
  const int srow = t >> 3;                         // 0..63
  const int vs = t & 15, vr = t >> 4;              // V staging: slot, row (0..31)
  const int vcsrc = ((vs & 8) | ((vs & 7) ^ (vr & 7))) * 8;  // 16-chunk swizzle
  // K=32 A-layout key-row remap (see header comment)
  const int krow0 = 8 * (lm >> 2) + 4 * ((lm >> 2) & 1) + (lm & 3);
  const int ks0 = krow0 & 7;
  const int krow1 = krow0 ^ 4;
  const int ks1 = ks0 ^ 4;
  const bf16x8 vones = {(short)0x3F80, (short)0x3F80, (short)0x3F80, (short)0x3F80,
                        (short)0x3F80, (short)0x3F80, (short)0x3F80, (short)0x3F80};

  // stage Q + first K/V tile (512 threads: 2 rounds each)
#pragma unroll
  for (int c = 0; c < 2; ++c) {
    gload_lds16(&qp[(size_t)(q0 + 64 * c + srow) * HD + fsw], &Qs[(64 * c + 8 * w) * 64]);
    gload_lds16(&kp[(size_t)(64 * c + srow) * HD + fsw], &Ksb[(64 * c + 8 * w) * 64]);
    gload_lds16(&vp[(size_t)(32 * c + vr) * L + vcsrc], &Vtb[(32 * c + 4 * w) * 128]);
  }
  __syncthreads();
  bf16x8 qf[2][2];
#pragma unroll
  for (int i = 0; i < 2; ++i)
#pragma unroll
    for (int kk = 0; kk < 2; ++kk)
      qf[i][kk] = *(const bf16x8*)&Qs[(wq * 32 + 16 * i + lm) * 64 + ((kk * 4 + lq) ^ swm) * 8];

  f32x4 ot[2][4] = {};   // O[qrow=32wq+16i+4lq+r][feat=16jf+lm], this wave's key-half
  f32x4 ot1[2] = {};     // row-sums (ones-column): lane rows 4lq+r (lm duplicated)

  for (int kt = 0; kt < L / 128; ++kt) {
    const int cur = kt & 1;
    const unsigned short* Kc = Ksb + cur * 8192;
    const unsigned short* Vc = Vtb + cur * 8192;
    // mask bytes FIRST (oldest vmcnt entries); each wave needs only its half
    unsigned char mby = mask[b * L + kt * 128 + 64 * wj + l];
    if (kt + 1 < L / 128) {
      const int nk0 = (kt + 1) * 128;
      unsigned short* Kd = Ksb + (cur ^ 1) * 8192;
      unsigned short* Vd = Vtb + (cur ^ 1) * 8192;
#pragma unroll
      for (int c = 0; c < 2; ++c) {
        gload_lds16(&kp[(size_t)(nk0 + 64 * c + srow) * HD + fsw], &Kd[(64 * c + 8 * w) * 64]);
        gload_lds16(&vp[(size_t)(32 * c + vr) * L + nk0 + vcsrc], &Vd[(32 * c + 4 * w) * 128]);
      }
    }
    unsigned long long mb = __ballot(mby != 0);

#pragma unroll
    for (int g = 0; g < 2; ++g) {
      const int gg = 2 * wj + g;            // 32-key group within 128-key tile
      const unsigned short* Kg = Kc + 32 * gg * 64;
      // remapped K fragments: rows krow0 (->j per lq parity) and krow1
      bf16x8 ka0 = *(const bf16x8*)&Kg[krow0 * 64 + ((0 + lq) ^ ks0) * 8];
      bf16x8 ka1 = *(const bf16x8*)&Kg[krow0 * 64 + ((4 + lq) ^ ks0) * 8];
      bf16x8 kb0 = *(const bf16x8*)&Kg[krow1 * 64 + ((0 + lq) ^ ks1) * 8];
      bf16x8 kb1 = *(const bf16x8*)&Kg[krow1 * 64 + ((4 + lq) ^ ks1) * 8];
      f32x4 stA[2], stB[2];
      __builtin_amdgcn_s_setprio(1);
#pragma unroll
      for (int i = 0; i < 2; ++i) {
        f32x4 a = {};
        a = __builtin_amdgcn_mfma_f32_16x16x32_bf16(ka0, qf[i][0], a, 0, 0, 0);
        a = __builtin_amdgcn_mfma_f32_16x16x32_bf16(ka1, qf[i][1], a, 0, 0, 0);
        stA[i] = a;
        f32x4 bq = {};
        bq = __builtin_amdgcn_mfma_f32_16x16x32_bf16(kb0, qf[i][0], bq, 0, 0, 0);
        bq = __builtin_amdgcn_mfma_f32_16x16x32_bf16(kb1, qf[i][1], bq, 0, 0, 0);
        stB[i] = bq;
      }
      __builtin_amdgcn_s_setprio(0);
      if (mb) {  // wave-uniform; all-false mask skips this
        // stA lane keys: 32g + 8lq + 4(lq&1) + r; stB: ^4
        const int shA = 32 * g + 8 * lq + 4 * (lq & 1);
        unsigned bitsA = (unsigned)(mb >> shA);
        unsigned bitsB = (unsigned)(mb >> (shA ^ 4));
#pragma unroll
        for (int i = 0; i < 2; ++i)
#pragma unroll
          for (int r = 0; r < 4; ++r) {
            if ((bitsA >> r) & 1u) stA[i][r] = -1e30f;
            if ((bitsB >> r) & 1u) stB[i][r] = -1e30f;
          }
      }
      // p = exp2(s); build K=32 A-fragment (lq parity selects quad order)
      union { uint4 q; bf16x8 v; } pa[2];
      const bool sw = (lq & 1) != 0;
#pragma unroll
      for (int i = 0; i < 2; ++i) {
        float eA[4], eB[4];
#pragma unroll
        for (int r = 0; r < 4; ++r) {
          eA[r] = __builtin_amdgcn_exp2f(stA[i][r]);
          eB[r] = __builtin_amdgcn_exp2f(stB[i][r]);
        }
        unsigned a01 = pack2bf_trunc(eA[0], eA[1]);
        unsigned a23 = pack2bf_trunc(eA[2], eA[3]);
        unsigned b01 = pack2bf_trunc(eB[0], eB[1]);
        unsigned b23 = pack2bf_trunc(eB[2], eB[3]);
        pa[i].q.x = sw ? b01 : a01;
        pa[i].q.y = sw ? b23 : a23;
        pa[i].q.z = sw ? a01 : b01;
        pa[i].q.w = sw ? a23 : b23;
      }
      // O += P@V for this 32-key group (b128 V^T reads, K=32 MFMA);
      // ones-column MFMA accumulates row-sums into ot1 (C-layout rows).
      const int kc = 4 * gg + lq;                    // 8-key chunk index
      const int slot = (kc & 8) | ((kc & 7) ^ swm);
      __builtin_amdgcn_s_setprio(1);
#pragma unroll
      for (int jf = 0; jf < 4; ++jf) {
        bf16x8 vb = *(const bf16x8*)&Vc[(16 * jf + lm) * 128 + slot * 8];
#pragma unroll
        for (int i = 0; i < 2; ++i)
          ot[i][jf] = __builtin_amdgcn_mfma_f32_16x16x32_bf16(pa[i].v, vb, ot[i][jf], 0, 0, 0);
      }
#pragma unroll
      for (int i = 0; i < 2; ++i)
        ot1[i] = __builtin_amdgcn_mfma_f32_16x16x32_bf16(pa[i].v, vones, ot1[i], 0, 0, 0);
      __builtin_amdgcn_s_setprio(0);
    }
    __syncthreads();
  }

  // ---- epilogue: combine wave-pair partials, normalize, store ----
  // All K/V/Q LDS is dead past the final loop barrier; carve scratch:
  float* Obuf = (float*)smem;                 // [64 cols][stride 132] f32, 33.8 KB
  unsigned short* Es = smem + 20480;          // byte 40960; stride-72 rows, 18.4 KB
  float* Sred = (float*)(smem + 35840);       // byte 71680; 8*32 floats

  // publish C-layout row sums (rows 32wq+16i+4lq+r); lm lanes duplicate
  if (lm == 0) {
#pragma unroll
    for (int i = 0; i < 2; ++i)
#pragma unroll
      for (int r = 0; r < 4; ++r)
        Sred[w * 32 + 16 * i + 4 * lq + r] = ot1[i][r];
  }
  if (wj) {
    // upper waves park raw O partials (col-major, r contiguous -> f32x4)
#pragma unroll
    for (int i = 0; i < 2; ++i)
#pragma unroll
      for (int jf = 0; jf < 4; ++jf)
        *(f32x4*)&Obuf[(16 * jf + lm) * 132 + wq * 32 + 16 * i + 4 * lq] = ot[i][jf];
  }
  __syncthreads();
  if (!wj) {
    float rlq[2][4];
#pragma unroll
    for (int i = 0; i < 2; ++i)
#pragma unroll
      for (int r = 0; r < 4; ++r)
        rlq[i][r] = 1.0f / (ot1[i][r] + Sred[(w + 4) * 32 + 16 * i + 4 * lq + r]);
#pragma unroll
    for (int i = 0; i < 2; ++i)
#pragma unroll
      for (int jf = 0; jf < 4; ++jf) {
        f32x4 po = *(const f32x4*)&Obuf[(16 * jf + lm) * 132 + wq * 32 + 16 * i + 4 * lq];
        ot[i][jf] += po;
      }
    // O rows -> Es (stride 72) -> coalesced 16B stores.
    // Safe without barrier: each wave touches only its own 32 rows.
#pragma unroll
    for (int i = 0; i < 2; ++i)
#pragma unroll
      for (int jf = 0; jf < 4; ++jf)
#pragma unroll
        for (int r = 0; r < 4; ++r)
          Es[(wq * 32 + 16 * i + 4 * lq + r) * 72 + 16 * jf + lm] =
              f2bf(ot[i][jf][r] * rlq[i][r]);
    int row = l >> 1, half = l & 1;
    size_t obase = ((size_t)(b * L + q0 + wq * 32 + row)) * D + h * HD + half * 32;
#pragma unroll
    for (int c = 0; c < 4; ++c) {
      uint4 u = *(const uint4*)&Es[(wq * 32 + row) * 72 + half * 32 + c * 8];
      *(uint4*)&ctx[obase + c * 8] = u;
    }
  }
}

// ---------------- output projection GEMM (BK=64, 2-phase dbuf) ----------
// out = ctx@Wo + bo. XCD-chunked block swizzle (bijective: 512 = 8 x 64)
// + 2-phase gload_lds prefetch (grid 512 = exactly 2 blocks/CU: no
// residency loss from the 48 KB LDS, unlike proj's 768-grid case).
__global__ __launch_bounds__(256) void outgemm_kernel(
    const unsigned short* __restrict__ ctx, const unsigned short* __restrict__ WoT,
    const float* __restrict__ bo, float* __restrict__ out) {
  __shared__ __align__(16) unsigned short smem[24576];  // 48 KB: 2x(As+Bs)
  const int lin = blockIdx.x + 8 * blockIdx.y;
  const int nlin = (lin & 7) * 64 + (lin >> 3);   // XCD chunk remap
  const int m0 = (nlin >> 3) * 64, n0 = (nlin & 7) * 128;
  const int t = threadIdx.x, l = t & 63, w = t >> 6;
  const int wm = w >> 1, wn = w & 1;
  const int lm = l & 15, lq = l >> 4;
  const int srow8 = t >> 3;
  const int fsw = ((t & 7) ^ ((t >> 3) & 7)) * 8;
  const int swm = lm & 7;

  auto stage = [&](int kt, int bsel) {
    const int kb = kt * 64;
    unsigned short* As = smem + bsel * 12288;
    unsigned short* Bs = As + 4096;
#pragma unroll
    for (int c = 0; c < 2; ++c)
      gload_lds16(&ctx[(size_t)(m0 + 32 * c + srow8) * D + kb + fsw],
                  &As[(32 * c + 8 * w) * 64]);
#pragma unroll
    for (int c = 0; c < 4; ++c)
      gload_lds16(&WoT[(size_t)(n0 + 32 * c + srow8) * D + kb + fsw],
                  &Bs[(32 * c + 8 * w) * 64]);
  };

  f32x4 acc[2][4] = {};
  stage(0, 0);
  __syncthreads();
  for (int kt = 0; kt < D / 64; ++kt) {
    const int cur = kt & 1;
    if (kt + 1 < D / 64) stage(kt + 1, cur ^ 1);
    const unsigned short* As = smem + cur * 12288;
    const unsigned short* Bs = As + 4096;
#pragma unroll
    for (int kk = 0; kk < 2; ++kk) {
      bf16x8 af[2], bf[4];
#pragma unroll
      for (int i = 0; i < 2; ++i)
        af[i] = *(const bf16x8*)&As[(32 * wm + 16 * i + lm) * 64 + ((kk * 4 + lq) ^ swm) * 8];
#pragma unroll
      for (int j = 0; j < 4; ++j)
        bf[j] = *(const bf16x8*)&Bs[(64 * wn + 16 * j + lm) * 64 + ((kk * 4 + lq) ^ swm) * 8];
#pragma unroll
      for (int i = 0; i < 2; ++i)
#pragma unroll
        for (int j = 0; j < 4; ++j)
          acc[i][j] = __builtin_amdgcn_mfma_f32_16x16x32_bf16(af[i], bf[j], acc[i][j], 0, 0, 0);
    }
    __syncthreads();
  }
#pragma unroll
  for (int i = 0; i < 2; ++i)
#pragma unroll
    for (int j = 0; j < 4; ++j)
#pragma unroll
      for (int r = 0; r < 4; ++r) {
        int grow = m0 + 32 * wm + 16 * i + lq * 4 + r;
        int gcol = n0 + 64 * wn + 16 * j + lm;
        out[(size_t)grow * D + gcol] = acc[i][j][r] + bo[gcol];
      }
}

extern "C" void kernel_launch(void* const* d_in, const int* in_sizes, int n_in,
                              void* d_out, int out_size, void* d_ws, size_t ws_size,
                              hipStream_t stream) {
  const float* x    = (const float*)d_in[0];
  const float* subj = (const float*)d_in[1];
  const unsigned char* mask = (const unsigned char*)d_in[2];
  const float* Wq = (const float*)d_in[3];
  const float* Wk = (const float*)d_in[4];
  const float* Wv = (const float*)d_in[5];
  const float* Wo = (const float*)d_in[6];
  const float* bo = (const float*)d_in[7];
  const float* Wsq = (const float*)d_in[8];
  const float* bsq = (const float*)d_in[9];
  const float* Wsk = (const float*)d_in[10];
  const float* bsk = (const float*)d_in[11];
  float* out = (float*)d_out;
  char* ws = (char*)d_ws;

  // workspace layout (bytes)
  unsigned short* xb  = (unsigned short*)(ws);                    // 8 MB
  unsigned short* WT4 = (unsigned short*)(ws + (8ull  << 20));    // 8 MB
  unsigned short* qk  = (unsigned short*)(ws + (16ull << 20));    // 16 MB (q,k)
  unsigned short* ctx = (unsigned short*)(ws + (32ull << 20));    // 8 MB
  unsigned short* vT  = (unsigned short*)(ws + (40ull << 20));    // 8 MB
  float* sq = (float*)(ws + (48ull << 20));                       // 8 KB
  float* sk = sq + B * D;

  hipLaunchKernelGGL(prep_kernel, dim3(3088), dim3(256), 0, stream,
                     Wq, Wk, Wv, Wo, x, subj, Wsq, bsq, Wsk, bsk, WT4, xb, sq, sk);
  hipLaunchKernelGGL(proj_kernel, dim3(8, 32, 3), dim3(256), 0, stream,
                     xb, WT4, sq, sk, qk, vT);
  hipLaunchKernelGGL(attn_kernel, dim3(512), dim3(512), 0, stream,
                     qk, qk + (size_t)M * D, vT, mask, ctx);
  hipLaunchKernelGGL(outgemm_kernel, dim3(8, 64, 1), dim3(256), 0, stream, ctx,
                     WT4 + 3ull * D * D, bo, out);
}

// Round 12
// 190.819 us; speedup vs baseline: 1.4408x; 1.0418x over previous
//
#include <hip/hip_runtime.h>
#include <hip/hip_bf16.h>
#include <math.h>

#define DEV __device__ __forceinline__

typedef short bf16x8 __attribute__((ext_vector_type(8)));
typedef short bf16x4 __attribute__((ext_vector_type(4)));
typedef float f32x4 __attribute__((ext_vector_type(4)));

static constexpr int D  = 1024;
static constexpr int H  = 16;
static constexpr int HD = 64;
static constexpr int DS = 64;
static constexpr int B  = 2;
static constexpr int L  = 2048;
static constexpr int M  = B * L;   // 4096

// softmax scale * log2(e), folded into q at projection time (exp2-based
// softmax, no max subtraction: scores bounded far below exp2 overflow;
// masked scores (-1e30) give exp2 -> 0 exactly).
static constexpr float QSCALE = 0.18033688011112042f; // 0.125 * log2(e)

DEV unsigned short f2bf(float f) {
  union { float f; unsigned u; } x; x.f = f;
  unsigned r = (x.u + 0x7FFFu + ((x.u >> 16) & 1u)) >> 16;
  return (unsigned short)r;
}

DEV unsigned pack2bf(float a, float b) {
  return (unsigned)f2bf(a) | ((unsigned)f2bf(b) << 16);
}

// truncation pack (P only: truncation bias cancels between Sum(p*v) and Sum(p))
// single v_perm_b32: bytes [ua.b2, ua.b3, ub.b2, ub.b3]
DEV unsigned pack2bf_trunc(float a, float b) {
  union { float f; unsigned u; } ua{a}, ub{b};
  return __builtin_amdgcn_perm(ub.u, ua.u, 0x07060302u);
}

// async global->LDS, 16B per lane; LDS dest = wave-uniform base + 16*lane.
DEV void gload_lds16(const void* g, void* l) {
  __builtin_amdgcn_global_load_lds(
      (const __attribute__((address_space(1))) unsigned int*)g,
      (__attribute__((address_space(3))) unsigned int*)l, 16, 0, 0);
}

// ---------------- merged preprocessing ----------------
// blocks [0,1024): W transpose+bf16 (vectorized: float4 reads, ushort4
// transposed stores -- scalar 2B bf16 stores were Common-mistake #2);
// [1024,3072): x->bf16; [3072,3088): sq/sk
__global__ __launch_bounds__(256) void prep_kernel(
    const float* __restrict__ Wq, const float* __restrict__ Wk,
    const float* __restrict__ Wv, const float* __restrict__ Wo,
    const float* __restrict__ x, const float* __restrict__ subj,
    const float* __restrict__ Wsq, const float* __restrict__ bsq,
    const float* __restrict__ Wsk, const float* __restrict__ bsk,
    unsigned short* __restrict__ WT4, unsigned short* __restrict__ xb,
    float* __restrict__ sq, float* __restrict__ sk) {
  __shared__ float tile[64][65];
  const int blk = blockIdx.x, t = threadIdx.x;
  if (blk < 1024) {
    const int z = blk >> 8, idx = blk & 255;
    const float* W = z == 0 ? Wq : z == 1 ? Wk : z == 2 ? Wv : Wo;
    unsigned short* dst = WT4 + (size_t)z * D * D;
    const int n0 = (idx & 15) * 64, k0 = (idx >> 4) * 64;
    const int c4 = (t & 15) * 4;   // 4-col group
    const int r16 = t >> 4;        // 0..15
    // read: 64x64 fp32 tile, float4 per lane (16B coalesced)
#pragma unroll
    for (int rr = 0; rr < 4; ++rr) {
      int row = r16 + rr * 16;
      float4 v = *(const float4*)&W[(size_t)(k0 + row) * D + n0 + c4];
      tile[row][c4 + 0] = v.x;
      tile[row][c4 + 1] = v.y;
      tile[row][c4 + 2] = v.z;
      tile[row][c4 + 3] = v.w;
    }
    __syncthreads();
    // write transposed: dst[n][k] = tile[k][n], ushort4 per lane (8B).
    // LDS read banks: (4(l&15)+j)*65 + (l>>4) -> 2-way alias only (free).
#pragma unroll
    for (int rr = 0; rr < 4; ++rr) {
      int nrow = r16 + rr * 16;
      ushort4 u;
      u.x = f2bf(tile[c4 + 0][nrow]);
      u.y = f2bf(tile[c4 + 1][nrow]);
      u.z = f2bf(tile[c4 + 2][nrow]);
      u.w = f2bf(tile[c4 + 3][nrow]);
      *(ushort4*)&dst[(size_t)(n0 + nrow) * D + k0 + c4] = u;
    }
  } else if (blk < 3072) {
    size_t g = (size_t)(blk - 1024) * 256 + t;
    const float4* xf = (const float4*)x;
    float4 a = xf[2 * g], b = xf[2 * g + 1];
    union { unsigned short s[8]; uint4 v; } o;
    o.s[0] = f2bf(a.x); o.s[1] = f2bf(a.y); o.s[2] = f2bf(a.z); o.s[3] = f2bf(a.w);
    o.s[4] = f2bf(b.x); o.s[5] = f2bf(b.y); o.s[6] = f2bf(b.z); o.s[7] = f2bf(b.w);
    ((uint4*)xb)[g] = o.v;
  } else {
    int g = (blk - 3072) * 256 + t;  // [0, 4096)
    int ty = g >> 11, b = (g >> 10) & 1, n = g & 1023;
    const float* W = ty ? Wsk : Wsq;
    const float* bias = ty ? bsk : bsq;
    float s = bias[n];
#pragma unroll 8
    for (int d = 0; d < DS; ++d) s += subj[b * DS + d] * W[d * D + n];
    (ty ? sk : sq)[b * D + n] = s;
  }
}

// ---------------- fused QKV projection GEMM (BK=64, 2-phase dbuf) -------
// z=0: q = (x@Wq + sq)*QSCALE -> qk[0]; z=1: k = x@Wk + sk -> qk[1]
// z=2: v = x@Wv written directly transposed to vT[B,H,64,L] (fused vtrans).
// XCD-chunked block swizzle (bijective: 768 = 8 XCDs x 96) keeps xb/W
// re-reads in the XCD-local L2 (FETCH 68.7 -> 29.8 MB, measured r4).
// 2-phase gload_lds prefetch: stage tile kt+1 into buf[cur^1] BEFORE
// computing tile kt (measured r5: proj 52.9 -> ~46 us). MEASURED OPTIMUM
// for this structure: BK=32 dbuf (r11: 54.3, more barrier drains) and
// reg-staging (r7/r8: spills, 205-308 MB scratch WRITE) are both worse;
// occupancy is pinned ~14% regardless of LDS footprint, so the 64 KB
// double-buffer costs nothing.
__global__ __launch_bounds__(256) void proj_kernel(
    const unsigned short* __restrict__ xb, const unsigned short* __restrict__ WT3,
    const float* __restrict__ sq, const float* __restrict__ sk,
    unsigned short* __restrict__ qk, unsigned short* __restrict__ vT) {
  __shared__ __align__(16) unsigned short smem[32768];  // 64 KB: 2x(As+Bs)
  const int lin = blockIdx.x + 8 * (blockIdx.y + 32 * blockIdx.z);
  const int nlin = (lin & 7) * 96 + (lin >> 3);   // XCD chunk remap
  const int z = nlin >> 8;
  const int rem = nlin & 255;
  const unsigned short* Wt = WT3 + (size_t)z * D * D;
  const int m0 = (rem >> 3) * 128, n0 = (rem & 7) * 128;
  const int t = threadIdx.x, l = t & 63, w = t >> 6;
  const int wm = w >> 1, wn = w & 1;
  const int lm = l & 15, lq = l >> 4;
  const int srow8 = t >> 3;
  const int fsw = ((t & 7) ^ ((t >> 3) & 7)) * 8;
  const int swm = lm & 7;

  auto stage = [&](int kt, int bsel) {
    const int kb = kt * 64;
    unsigned short* As = smem + bsel * 16384;
    unsigned short* Bs = As + 8192;
#pragma unroll
    for (int c = 0; c < 4; ++c) {
      int row = 32 * c + srow8;
      gload_lds16(&xb[(size_t)(m0 + row) * D + kb + fsw], &As[(32 * c + 8 * w) * 64]);
      gload_lds16(&Wt[(size_t)(n0 + row) * D + kb + fsw], &Bs[(32 * c + 8 * w) * 64]);
    }
  };

  f32x4 acc[4][4] = {};
  stage(0, 0);
  __syncthreads();
  for (int kt = 0; kt < D / 64; ++kt) {
    const int cur = kt & 1;
    if (kt + 1 < D / 64) stage(kt + 1, cur ^ 1);
    const unsigned short* As = smem + cur * 16384;
    const unsigned short* Bs = As + 8192;
#pragma unroll
    for (int kk = 0; kk < 2; ++kk) {
      bf16x8 af[4], bf[4];
#pragma unroll
      for (int i = 0; i < 4; ++i)
        af[i] = *(const bf16x8*)&As[(64 * wm + 16 * i + lm) * 64 + ((kk * 4 + lq) ^ swm) * 8];
#pragma unroll
      for (int j = 0; j < 4; ++j)
        bf[j] = *(const bf16x8*)&Bs[(64 * wn + 16 * j + lm) * 64 + ((kk * 4 + lq) ^ swm) * 8];
#pragma unroll
      for (int i = 0; i < 4; ++i)
#pragma unroll
        for (int j = 0; j < 4; ++j)
          acc[i][j] = __builtin_amdgcn_mfma_f32_16x16x32_bf16(af[i], bf[j], acc[i][j], 0, 0, 0);
    }
    __syncthreads();  // vmcnt(0): prefetch (issued pre-compute) has landed
  }
  if (z == 2) {
    // transpose epilogue: acc -> smem T[col][row] (stride 136) -> vT
    // (smem pool is dead past the final loop barrier)
#pragma unroll
    for (int i = 0; i < 4; ++i)
#pragma unroll
      for (int j = 0; j < 4; ++j) {
        int cr = 64 * wn + 16 * j + lm;
        int rr = 64 * wm + 16 * i + 4 * lq;
        uint2 u;
        u.x = pack2bf(acc[i][j][0], acc[i][j][1]);
        u.y = pack2bf(acc[i][j][2], acc[i][j][3]);
        *(uint2*)&smem[cr * 136 + rr] = u;
      }
    __syncthreads();
    const int cr = t >> 1, half = t & 1;
    const int bb = m0 >> 11, l0 = m0 & (L - 1);
    const int gcol = n0 + cr, h = gcol >> 6, hd = gcol & 63;
    size_t dbase = ((size_t)(bb * H + h) * HD + hd) * L + l0 + half * 64;
#pragma unroll
    for (int c = 0; c < 8; ++c) {
      uint4 u = *(const uint4*)&smem[cr * 136 + half * 64 + c * 8];
      *(uint4*)&vT[dbase + c * 8] = u;
    }
  } else {
    unsigned short* dst = qk + (size_t)z * M * D;
    const float* bias = z == 0 ? sq : sk;
    const float post = z == 0 ? QSCALE : 1.0f;
    // stage [row][col] into smem, then fully-coalesced 16B stores
#pragma unroll
    for (int i = 0; i < 4; ++i)
#pragma unroll
      for (int j = 0; j < 4; ++j)
#pragma unroll
        for (int r = 0; r < 4; ++r) {
          int rr = 64 * wm + 16 * i + 4 * lq + r;
          int cc = 64 * wn + 16 * j + lm;
          float v = (acc[i][j][r] + bias[((m0 + rr) >> 11) * D + n0 + cc]) * post;
          smem[rr * 136 + cc] = f2bf(v);
        }
    __syncthreads();
    const int row = t >> 1, half = t & 1;
    const int bb = m0 >> 11, ll = (m0 & (L - 1)) + row;
    const int h0 = (n0 >> 6) + half;
    size_t dbase = ((size_t)(bb * H + h0) * L + ll) * HD;
#pragma unroll
    for (int c = 0; c < 8; ++c) {
      uint4 u = *(const uint4*)&smem[row * 136 + half * 64 + c * 8];
      *(uint4*)&dst[dbase + c * 8] = u;
    }
  }
}

// ---------------- flash attention (BK=128, register P, dbuf) ----------
// grid 512 XCD-swizzled; block 512 = 8 waves. Wave-pair key-split:
// wave w owns q-rows 32*(w&3)..+31 and 64 keys (2 groups of 32) of each
// 128-key tile. PV uses full-width mfma_f32_16x16x32_bf16 over 32-key
// groups via the QK^T A-operand K-row REMAP (see krow0/krow1).
// Row-sums are computed by an extra ones-column MFMA per group
// (mfma(pa, ones, ot1)): per-lane C-layout sums of the SAME truncated
// bf16 p-values used in PV (truncation bias cancels exactly in the ratio),
// eliminating the scalar adds + all epilogue shuffles.
// s_setprio(1) wraps the MFMA clusters (T5).
// Mask bytes are loaded BEFORE the prefetch DMAs so the ballot's vmcnt wait
// does not drain the prefetch (FIFO vmcnt: mask loads are the oldest).
__global__ __launch_bounds__(512, 4) void attn_kernel(
    const unsigned short* __restrict__ q_hm, const unsigned short* __restrict__ k_hm,
    const unsigned short* __restrict__ vT, const unsigned char* __restrict__ mask,
    unsigned short* __restrict__ ctx) {
  __shared__ __align__(16) unsigned short smem[40960];  // 80 KB pool
  unsigned short* Qs  = smem;                // 128*64   (16 KB)
  unsigned short* Ksb = smem + 8192;         // 2*128*64 (32 KB) [buf][key][feat]
  unsigned short* Vtb = smem + 24576;        // 2*64*128 (32 KB) [buf][feat][key]
  const int bx = blockIdx.x;
  const int rest = bx >> 3;
  const int bhid = (bx & 7) + 8 * (rest >> 4);
  const int q0 = (rest & 15) * 128;
  const int h = bhid & 15, b = bhid >> 4;
  const size_t bh = (size_t)(b * H + h);
  const unsigned short* qp = q_hm + bh * L * HD;
  const unsigned short* kp = k_hm + bh * L * HD;
  const unsigned short* vp = vT + bh * HD * L;
  const int t = threadIdx.x, l = t & 63, w = t >> 6;
  const int wq = w & 3, wj = w >> 2;               // q-row group, key half
  const int lm = l & 15, lq = l >> 4;
  const int fsw = ((t & 7) ^ ((t >> 3) & 7)) * 8;  // 8-chunk swizzle (64-wide rows)
  const int swm = lm & 7;
  const int srow = t >> 3;                         // 0..63
  const int vs = t & 15, vr = t >> 4;              // V staging: slot, row (0..31)
  const int vcsrc = ((vs & 8) | ((vs & 7) ^ (vr & 7))) * 8;  // 16-chunk swizzle
  // K=32 A-layout key-row remap (see header comment)
  const int krow0 = 8 * (lm >> 2) + 4 * ((lm >> 2) & 1) + (lm & 3);
  const int ks0 = krow0 & 7;
  const int krow1 = krow0 ^ 4;
  const int ks1 = ks0 ^ 4;
  const bf16x8 vones = {(short)0x3F80, (short)0x3F80, (short)0x3F80, (short)0x3F80,
                        (short)0x3F80, (short)0x3F80, (short)0x3F80, (short)0x3F80};

  // stage Q + first K/V tile (512 threads: 2 rounds each)
#pragma unroll
  for (int c = 0; c < 2; ++c) {
    gload_lds16(&qp[(size_t)(q0 + 64 * c + srow) * HD + fsw], &Qs[(64 * c + 8 * w) * 64]);
    gload_lds16(&kp[(size_t)(64 * c + srow) * HD + fsw], &Ksb[(64 * c + 8 * w) * 64]);
    gload_lds16(&vp[(size_t)(32 * c + vr) * L + vcsrc], &Vtb[(32 * c + 4 * w) * 128]);
  }
  __syncthreads();
  bf16x8 qf[2][2];
#pragma unroll
  for (int i = 0; i < 2; ++i)
#pragma unroll
    for (int kk = 0; kk < 2; ++kk)
      qf[i][kk] = *(const bf16x8*)&Qs[(wq * 32 + 16 * i + lm) * 64 + ((kk * 4 + lq) ^ swm) * 8];

  f32x4 ot[2][4] = {};   // O[qrow=32wq+16i+4lq+r][feat=16jf+lm], this wave's key-half
  f32x4 ot1[2] = {};     // row-sums (ones-column): lane rows 4lq+r (lm duplicated)

  for (int kt = 0; kt < L / 128; ++kt) {
    const int cur = kt & 1;
    const unsigned short* Kc = Ksb + cur * 8192;
    const unsigned short* Vc = Vtb + cur * 8192;
    // mask bytes FIRST (oldest vmcnt entries); each wave needs only its half
    unsigned char mby = mask[b * L + kt * 128 + 64 * wj + l];
    if (kt + 1 < L / 128) {
      const int nk0 = (kt + 1) * 128;
      unsigned short* Kd = Ksb + (cur ^ 1) * 8192;
      unsigned short* Vd = Vtb + (cur ^ 1) * 8192;
#pragma unroll
      for (int c = 0; c < 2; ++c) {
        gload_lds16(&kp[(size_t)(nk0 + 64 * c + srow) * HD + fsw], &Kd[(64 * c + 8 * w) * 64]);
        gload_lds16(&vp[(size_t)(32 * c + vr) * L + nk0 + vcsrc], &Vd[(32 * c + 4 * w) * 128]);
      }
    }
    unsigned long long mb = __ballot(mby != 0);

#pragma unroll
    for (int g = 0; g < 2; ++g) {
      const int gg = 2 * wj + g;            // 32-key group within 128-key tile
      const unsigned short* Kg = Kc + 32 * gg * 64;
      // remapped K fragments: rows krow0 (->j per lq parity) and krow1
      bf16x8 ka0 = *(const bf16x8*)&Kg[krow0 * 64 + ((0 + lq) ^ ks0) * 8];
      bf16x8 ka1 = *(const bf16x8*)&Kg[krow0 * 64 + ((4 + lq) ^ ks0) * 8];
      bf16x8 kb0 = *(const bf16x8*)&Kg[krow1 * 64 + ((0 + lq) ^ ks1) * 8];
      bf16x8 kb1 = *(const bf16x8*)&Kg[krow1 * 64 + ((4 + lq) ^ ks1) * 8];
      f32x4 stA[2], stB[2];
      __builtin_amdgcn_s_setprio(1);
#pragma unroll
      for (int i = 0; i < 2; ++i) {
        f32x4 a = {};
        a = __builtin_amdgcn_mfma_f32_16x16x32_bf16(ka0, qf[i][0], a, 0, 0, 0);
        a = __builtin_amdgcn_mfma_f32_16x16x32_bf16(ka1, qf[i][1], a, 0, 0, 0);
        stA[i] = a;
        f32x4 bq = {};
        bq = __builtin_amdgcn_mfma_f32_16x16x32_bf16(kb0, qf[i][0], bq, 0, 0, 0);
        bq = __builtin_amdgcn_mfma_f32_16x16x32_bf16(kb1, qf[i][1], bq, 0, 0, 0);
        stB[i] = bq;
      }
      __builtin_amdgcn_s_setprio(0);
      if (mb) {  // wave-uniform; all-false mask skips this
        // stA lane keys: 32g + 8lq + 4(lq&1) + r; stB: ^4
        const int shA = 32 * g + 8 * lq + 4 * (lq & 1);
        unsigned bitsA = (unsigned)(mb >> shA);
        unsigned bitsB = (unsigned)(mb >> (shA ^ 4));
#pragma unroll
        for (int i = 0; i < 2; ++i)
#pragma unroll
          for (int r = 0; r < 4; ++r) {
            if ((bitsA >> r) & 1u) stA[i][r] = -1e30f;
            if ((bitsB >> r) & 1u) stB[i][r] = -1e30f;
          }
      }
      // p = exp2(s); build K=32 A-fragment (lq parity selects quad order)
      union { uint4 q; bf16x8 v; } pa[2];
      const bool sw = (lq & 1) != 0;
#pragma unroll
      for (int i = 0; i < 2; ++i) {
        float eA[4], eB[4];
#pragma unroll
        for (int r = 0; r < 4; ++r) {
          eA[r] = __builtin_amdgcn_exp2f(stA[i][r]);
          eB[r] = __builtin_amdgcn_exp2f(stB[i][r]);
        }
        unsigned a01 = pack2bf_trunc(eA[0], eA[1]);
        unsigned a23 = pack2bf_trunc(eA[2], eA[3]);
        unsigned b01 = pack2bf_trunc(eB[0], eB[1]);
        unsigned b23 = pack2bf_trunc(eB[2], eB[3]);
        pa[i].q.x = sw ? b01 : a01;
        pa[i].q.y = sw ? b23 : a23;
        pa[i].q.z = sw ? a01 : b01;
        pa[i].q.w = sw ? a23 : b23;
      }
      // O += P@V for this 32-key group (b128 V^T reads, K=32 MFMA);
      // ones-column MFMA accumulates row-sums into ot1 (C-layout rows).
      const int kc = 4 * gg + lq;                    // 8-key chunk index
      const int slot = (kc & 8) | ((kc & 7) ^ swm);
      __builtin_amdgcn_s_setprio(1);
#pragma unroll
      for (int jf = 0; jf < 4; ++jf) {
        bf16x8 vb = *(const bf16x8*)&Vc[(16 * jf + lm) * 128 + slot * 8];
#pragma unroll
        for (int i = 0; i < 2; ++i)
          ot[i][jf] = __builtin_amdgcn_mfma_f32_16x16x32_bf16(pa[i].v, vb, ot[i][jf], 0, 0, 0);
      }
#pragma unroll
      for (int i = 0; i < 2; ++i)
        ot1[i] = __builtin_amdgcn_mfma_f32_16x16x32_bf16(pa[i].v, vones, ot1[i], 0, 0, 0);
      __builtin_amdgcn_s_setprio(0);
    }
    __syncthreads();
  }

  // ---- epilogue: combine wave-pair partials, normalize, store ----
  // All K/V/Q LDS is dead past the final loop barrier; carve scratch:
  float* Obuf = (float*)smem;                 // [64 cols][stride 132] f32, 33.8 KB
  unsigned short* Es = smem + 20480;          // byte 40960; stride-72 rows, 18.4 KB
  float* Sred = (float*)(smem + 35840);       // byte 71680; 8*32 floats

  // publish C-layout row sums (rows 32wq+16i+4lq+r); lm lanes duplicate
  if (lm == 0) {
#pragma unroll
    for (int i = 0; i < 2; ++i)
#pragma unroll
      for (int r = 0; r < 4; ++r)
        Sred[w * 32 + 16 * i + 4 * lq + r] = ot1[i][r];
  }
  if (wj) {
    // upper waves park raw O partials (col-major, r contiguous -> f32x4)
#pragma unroll
    for (int i = 0; i < 2; ++i)
#pragma unroll
      for (int jf = 0; jf < 4; ++jf)
        *(f32x4*)&Obuf[(16 * jf + lm) * 132 + wq * 32 + 16 * i + 4 * lq] = ot[i][jf];
  }
  __syncthreads();
  if (!wj) {
    float rlq[2][4];
#pragma unroll
    for (int i = 0; i < 2; ++i)
#pragma unroll
      for (int r = 0; r < 4; ++r)
        rlq[i][r] = 1.0f / (ot1[i][r] + Sred[(w + 4) * 32 + 16 * i + 4 * lq + r]);
#pragma unroll
    for (int i = 0; i < 2; ++i)
#pragma unroll
      for (int jf = 0; jf < 4; ++jf) {
        f32x4 po = *(const f32x4*)&Obuf[(16 * jf + lm) * 132 + wq * 32 + 16 * i + 4 * lq];
        ot[i][jf] += po;
      }
    // O rows -> Es (stride 72) -> coalesced 16B stores.
    // Safe without barrier: each wave touches only its own 32 rows.
#pragma unroll
    for (int i = 0; i < 2; ++i)
#pragma unroll
      for (int jf = 0; jf < 4; ++jf)
#pragma unroll
        for (int r = 0; r < 4; ++r)
          Es[(wq * 32 + 16 * i + 4 * lq + r) * 72 + 16 * jf + lm] =
              f2bf(ot[i][jf][r] * rlq[i][r]);
    int row = l >> 1, half = l & 1;
    size_t obase = ((size_t)(b * L + q0 + wq * 32 + row)) * D + h * HD + half * 32;
#pragma unroll
    for (int c = 0; c < 4; ++c) {
      uint4 u = *(const uint4*)&Es[(wq * 32 + row) * 72 + half * 32 + c * 8];
      *(uint4*)&ctx[obase + c * 8] = u;
    }
  }
}

// ---------------- output projection GEMM (BK=64, 2-phase dbuf) ----------
// out = ctx@Wo + bo. XCD-chunked block swizzle (bijective: 512 = 8 x 64)
// + 2-phase gload_lds prefetch (grid 512 = exactly 2 blocks/CU: no
// residency loss from the 48 KB LDS, unlike proj's 768-grid case).
__global__ __launch_bounds__(256) void outgemm_kernel(
    const unsigned short* __restrict__ ctx, const unsigned short* __restrict__ WoT,
    const float* __restrict__ bo, float* __restrict__ out) {
  __shared__ __align__(16) unsigned short smem[24576];  // 48 KB: 2x(As+Bs)
  const int lin = blockIdx.x + 8 * blockIdx.y;
  const int nlin = (lin & 7) * 64 + (lin >> 3);   // XCD chunk remap
  const int m0 = (nlin >> 3) * 64, n0 = (nlin & 7) * 128;
  const int t = threadIdx.x, l = t & 63, w = t >> 6;
  const int wm = w >> 1, wn = w & 1;
  const int lm = l & 15, lq = l >> 4;
  const int srow8 = t >> 3;
  const int fsw = ((t & 7) ^ ((t >> 3) & 7)) * 8;
  const int swm = lm & 7;

  auto stage = [&](int kt, int bsel) {
    const int kb = kt * 64;
    unsigned short* As = smem + bsel * 12288;
    unsigned short* Bs = As + 4096;
#pragma unroll
    for (int c = 0; c < 2; ++c)
      gload_lds16(&ctx[(size_t)(m0 + 32 * c + srow8) * D + kb + fsw],
                  &As[(32 * c + 8 * w) * 64]);
#pragma unroll
    for (int c = 0; c < 4; ++c)
      gload_lds16(&WoT[(size_t)(n0 + 32 * c + srow8) * D + kb + fsw],
                  &Bs[(32 * c + 8 * w) * 64]);
  };

  f32x4 acc[2][4] = {};
  stage(0, 0);
  __syncthreads();
  for (int kt = 0; kt < D / 64; ++kt) {
    const int cur = kt & 1;
    if (kt + 1 < D / 64) stage(kt + 1, cur ^ 1);
    const unsigned short* As = smem + cur * 12288;
    const unsigned short* Bs = As + 4096;
#pragma unroll
    for (int kk = 0; kk < 2; ++kk) {
      bf16x8 af[2], bf[4];
#pragma unroll
      for (int i = 0; i < 2; ++i)
        af[i] = *(const bf16x8*)&As[(32 * wm + 16 * i + lm) * 64 + ((kk * 4 + lq) ^ swm) * 8];
#pragma unroll
      for (int j = 0; j < 4; ++j)
        bf[j] = *(const bf16x8*)&Bs[(64 * wn + 16 * j + lm) * 64 + ((kk * 4 + lq) ^ swm) * 8];
#pragma unroll
      for (int i = 0; i < 2; ++i)
#pragma unroll
        for (int j = 0; j < 4; ++j)
          acc[i][j] = __builtin_amdgcn_mfma_f32_16x16x32_bf16(af[i], bf[j], acc[i][j], 0, 0, 0);
    }
    __syncthreads();
  }
#pragma unroll
  for (int i = 0; i < 2; ++i)
#pragma unroll
    for (int j = 0; j < 4; ++j)
#pragma unroll
      for (int r = 0; r < 4; ++r) {
        int grow = m0 + 32 * wm + 16 * i + lq * 4 + r;
        int gcol = n0 + 64 * wn + 16 * j + lm;
        out[(size_t)grow * D + gcol] = acc[i][j][r] + bo[gcol];
      }
}

extern "C" void kernel_launch(void* const* d_in, const int* in_sizes, int n_in,
                              void* d_out, int out_size, void* d_ws, size_t ws_size,
                              hipStream_t stream) {
  const float* x    = (const float*)d_in[0];
  const float* subj = (const float*)d_in[1];
  const unsigned char* mask = (const unsigned char*)d_in[2];
  const float* Wq = (const float*)d_in[3];
  const float* Wk = (const float*)d_in[4];
  const float* Wv = (const float*)d_in[5];
  const float* Wo = (const float*)d_in[6];
  const float* bo = (const float*)d_in[7];
  const float* Wsq = (const float*)d_in[8];
  const float* bsq = (const float*)d_in[9];
  const float* Wsk = (const float*)d_in[10];
  const float* bsk = (const float*)d_in[11];
  float* out = (float*)d_out;
  char* ws = (char*)d_ws;

  // workspace layout (bytes)
  unsigned short* xb  = (unsigned short*)(ws);                    // 8 MB
  unsigned short* WT4 = (unsigned short*)(ws + (8ull  << 20));    // 8 MB
  unsigned short* qk  = (unsigned short*)(ws + (16ull << 20));    // 16 MB (q,k)
  unsigned short* ctx = (unsigned short*)(ws + (32ull << 20));    // 8 MB
  unsigned short* vT  = (unsigned short*)(ws + (40ull << 20));    // 8 MB
  float* sq = (float*)(ws + (48ull << 20));                       // 8 KB
  float* sk = sq + B * D;

  hipLaunchKernelGGL(prep_kernel, dim3(3088), dim3(256), 0, stream,
                     Wq, Wk, Wv, Wo, x, subj, Wsq, bsq, Wsk, bsk, WT4, xb, sq, sk);
  hipLaunchKernelGGL(proj_kernel, dim3(8, 32, 3), dim3(256), 0, stream,
                     xb, WT4, sq, sk, qk, vT);
  hipLaunchKernelGGL(attn_kernel, dim3(512), dim3(512), 0, stream,
                     qk, qk + (size_t)M * D, vT, mask, ctx);
  hipLaunchKernelGGL(outgemm_kernel, dim3(8, 64, 1), dim3(256), 0, stream, ctx,
                     WT4 + 3ull * D * D, bo, out);
}

// Round 13
// 189.124 us; speedup vs baseline: 1.4537x; 1.0090x over previous
//
#include <hip/hip_runtime.h>
#include <hip/hip_bf16.h>
#include <math.h>

#define DEV __device__ __forceinline__

typedef short bf16x8 __attribute__((ext_vector_type(8)));
typedef short bf16x4 __attribute__((ext_vector_type(4)));
typedef float f32x4 __attribute__((ext_vector_type(4)));

static constexpr int D  = 1024;
static constexpr int H  = 16;
static constexpr int HD = 64;
static constexpr int DS = 64;
static constexpr int B  = 2;
static constexpr int L  = 2048;
static constexpr int M  = B * L;   // 4096

// softmax scale * log2(e), folded into q at projection time (exp2-based
// softmax, no max subtraction: scores bounded far below exp2 overflow;
// masked scores (-1e30) give exp2 -> 0 exactly).
static constexpr float QSCALE = 0.18033688011112042f; // 0.125 * log2(e)

DEV unsigned short f2bf(float f) {
  union { float f; unsigned u; } x; x.f = f;
  unsigned r = (x.u + 0x7FFFu + ((x.u >> 16) & 1u)) >> 16;
  return (unsigned short)r;
}

DEV unsigned pack2bf(float a, float b) {
  return (unsigned)f2bf(a) | ((unsigned)f2bf(b) << 16);
}

// truncation pack (P only: truncation bias cancels between Sum(p*v) and Sum(p))
// single v_perm_b32: bytes [ua.b2, ua.b3, ub.b2, ub.b3]
DEV unsigned pack2bf_trunc(float a, float b) {
  union { float f; unsigned u; } ua{a}, ub{b};
  return __builtin_amdgcn_perm(ub.u, ua.u, 0x07060302u);
}

// async global->LDS, 16B per lane; LDS dest = wave-uniform base + 16*lane.
DEV void gload_lds16(const void* g, void* l) {
  __builtin_amdgcn_global_load_lds(
      (const __attribute__((address_space(1))) unsigned int*)g,
      (__attribute__((address_space(3))) unsigned int*)l, 16, 0, 0);
}

// ---------------- merged preprocessing ----------------
// blocks [0,1024): W transpose+bf16 (vectorized: float4 reads, ushort4
// transposed stores); [1024,3072): x->bf16; [3072,3088): sq/sk
__global__ __launch_bounds__(256) void prep_kernel(
    const float* __restrict__ Wq, const float* __restrict__ Wk,
    const float* __restrict__ Wv, const float* __restrict__ Wo,
    const float* __restrict__ x, const float* __restrict__ subj,
    const float* __restrict__ Wsq, const float* __restrict__ bsq,
    const float* __restrict__ Wsk, const float* __restrict__ bsk,
    unsigned short* __restrict__ WT4, unsigned short* __restrict__ xb,
    float* __restrict__ sq, float* __restrict__ sk) {
  __shared__ float tile[64][65];
  const int blk = blockIdx.x, t = threadIdx.x;
  if (blk < 1024) {
    const int z = blk >> 8, idx = blk & 255;
    const float* W = z == 0 ? Wq : z == 1 ? Wk : z == 2 ? Wv : Wo;
    unsigned short* dst = WT4 + (size_t)z * D * D;
    const int n0 = (idx & 15) * 64, k0 = (idx >> 4) * 64;
    const int c4 = (t & 15) * 4;   // 4-col group
    const int r16 = t >> 4;        // 0..15
#pragma unroll
    for (int rr = 0; rr < 4; ++rr) {
      int row = r16 + rr * 16;
      float4 v = *(const float4*)&W[(size_t)(k0 + row) * D + n0 + c4];
      tile[row][c4 + 0] = v.x;
      tile[row][c4 + 1] = v.y;
      tile[row][c4 + 2] = v.z;
      tile[row][c4 + 3] = v.w;
    }
    __syncthreads();
#pragma unroll
    for (int rr = 0; rr < 4; ++rr) {
      int nrow = r16 + rr * 16;
      ushort4 u;
      u.x = f2bf(tile[c4 + 0][nrow]);
      u.y = f2bf(tile[c4 + 1][nrow]);
      u.z = f2bf(tile[c4 + 2][nrow]);
      u.w = f2bf(tile[c4 + 3][nrow]);
      *(ushort4*)&dst[(size_t)(n0 + nrow) * D + k0 + c4] = u;
    }
  } else if (blk < 3072) {
    size_t g = (size_t)(blk - 1024) * 256 + t;
    const float4* xf = (const float4*)x;
    float4 a = xf[2 * g], b = xf[2 * g + 1];
    union { unsigned short s[8]; uint4 v; } o;
    o.s[0] = f2bf(a.x); o.s[1] = f2bf(a.y); o.s[2] = f2bf(a.z); o.s[3] = f2bf(a.w);
    o.s[4] = f2bf(b.x); o.s[5] = f2bf(b.y); o.s[6] = f2bf(b.z); o.s[7] = f2bf(b.w);
    ((uint4*)xb)[g] = o.v;
  } else {
    int g = (blk - 3072) * 256 + t;  // [0, 4096)
    int ty = g >> 11, b = (g >> 10) & 1, n = g & 1023;
    const float* W = ty ? Wsk : Wsq;
    const float* bias = ty ? bsk : bsq;
    float s = bias[n];
#pragma unroll 8
    for (int d = 0; d < DS; ++d) s += subj[b * DS + d] * W[d * D + n];
    (ty ? sk : sq)[b * D + n] = s;
  }
}

// ---------------- fused QKV projection GEMM -----------------------------
// BK=32, 4-buffer pipeline, counted vmcnt (T4): NEVER vmcnt(0) in the main
// loop. Prologue issues stages 0..2 (24 DMAs/wave outstanding). Per step:
//   s_waitcnt vmcnt(16)  -> my stage(kt) landed (kt+1, kt+2 in flight)
//   s_barrier            -> everyone's stage(kt) landed AND everyone
//                           finished compute(kt-1)
//   stage(kt+3)          -> overwrites buf (kt-1)%4: safe (all waves past
//                           compute(kt-1) via this barrier)
//   compute(kt)          -> reads buf kt%4
// Tail peels kt=30 (vmcnt 8) and kt=31 (vmcnt 0). One barrier per step vs
// the old full-drain __syncthreads (r4 arithmetic: ~2000 cyc stall/step vs
// ~600 cyc compute). 4 x 16 KB = 64 KB LDS (same 2 blocks/CU as r12).
// XCD-chunked swizzle (bijective 768 = 8 x 96) keeps xb/W in XCD-local L2.
// z=0: q=(x@Wq+sq)*QSCALE; z=1: k=x@Wk+sk; z=2: v -> vT (fused transpose).
__global__ __launch_bounds__(256) void proj_kernel(
    const unsigned short* __restrict__ xb, const unsigned short* __restrict__ WT3,
    const float* __restrict__ sq, const float* __restrict__ sk,
    unsigned short* __restrict__ qk, unsigned short* __restrict__ vT) {
  __shared__ __align__(16) unsigned short smem[32768];  // 64 KB: 4 bufs x 16 KB
  const int lin = blockIdx.x + 8 * (blockIdx.y + 32 * blockIdx.z);
  const int nlin = (lin & 7) * 96 + (lin >> 3);   // XCD chunk remap
  const int z = nlin >> 8;
  const int rem = nlin & 255;
  const unsigned short* Wt = WT3 + (size_t)z * D * D;
  const int m0 = (rem >> 3) * 128, n0 = (rem & 7) * 128;
  const int t = threadIdx.x, l = t & 63, w = t >> 6;
  const int wm = w >> 1, wn = w & 1;
  const int lm = l & 15, lq = l >> 4;
  const int srow4 = t >> 2;                        // 0..63
  const int fsw2 = ((t & 3) ^ ((t >> 3) & 3)) * 8; // 4-chunk swizzle (32-wide)
  const int sw2 = (lm >> 1) & 3;

  auto stage = [&](int kt) {
    const int kb = kt * 32;
    unsigned short* As = smem + (kt & 3) * 8192;   // 16 KB buf: As|Bs
    unsigned short* Bs = As + 4096;
#pragma unroll
    for (int c = 0; c < 2; ++c) {
      gload_lds16(&xb[(size_t)(m0 + 64 * c + srow4) * D + kb + fsw2],
                  &As[(64 * c + 16 * w) * 32]);
      gload_lds16(&Wt[(size_t)(n0 + 64 * c + srow4) * D + kb + fsw2],
                  &Bs[(64 * c + 16 * w) * 32]);
    }
  };

  f32x4 acc[4][4] = {};
  auto compute = [&](int kt) {
    const unsigned short* As = smem + (kt & 3) * 8192;
    const unsigned short* Bs = As + 4096;
    bf16x8 af[4], bf[4];
#pragma unroll
    for (int i = 0; i < 4; ++i)
      af[i] = *(const bf16x8*)&As[(64 * wm + 16 * i + lm) * 32 + ((lq ^ sw2) * 8)];
#pragma unroll
    for (int j = 0; j < 4; ++j)
      bf[j] = *(const bf16x8*)&Bs[(64 * wn + 16 * j + lm) * 32 + ((lq ^ sw2) * 8)];
#pragma unroll
    for (int i = 0; i < 4; ++i)
#pragma unroll
      for (int j = 0; j < 4; ++j)
        acc[i][j] = __builtin_amdgcn_mfma_f32_16x16x32_bf16(af[i], bf[j], acc[i][j], 0, 0, 0);
  };

  stage(0); stage(1); stage(2);   // 24 DMAs outstanding per wave
  for (int kt = 0; kt < 30; ++kt) {
    asm volatile("s_waitcnt vmcnt(16)" ::: "memory");
    __builtin_amdgcn_s_barrier();
    __builtin_amdgcn_sched_barrier(0);
    if (kt + 3 < 32) stage(kt + 3);
    compute(kt);
  }
  asm volatile("s_waitcnt vmcnt(8)" ::: "memory");
  __builtin_amdgcn_s_barrier();
  __builtin_amdgcn_sched_barrier(0);
  compute(30);
  asm volatile("s_waitcnt vmcnt(0)" ::: "memory");
  __builtin_amdgcn_s_barrier();
  __builtin_amdgcn_sched_barrier(0);
  compute(31);
  __syncthreads();   // all reads done before epilogue reuses the pool

  if (z == 2) {
    // transpose epilogue: acc -> smem T[col][row] (stride 136) -> vT
#pragma unroll
    for (int i = 0; i < 4; ++i)
#pragma unroll
      for (int j = 0; j < 4; ++j) {
        int cr = 64 * wn + 16 * j + lm;
        int rr = 64 * wm + 16 * i + 4 * lq;
        uint2 u;
        u.x = pack2bf(acc[i][j][0], acc[i][j][1]);
        u.y = pack2bf(acc[i][j][2], acc[i][j][3]);
        *(uint2*)&smem[cr * 136 + rr] = u;
      }
    __syncthreads();
    const int cr = t >> 1, half = t & 1;
    const int bb = m0 >> 11, l0 = m0 & (L - 1);
    const int gcol = n0 + cr, h = gcol >> 6, hd = gcol & 63;
    size_t dbase = ((size_t)(bb * H + h) * HD + hd) * L + l0 + half * 64;
#pragma unroll
    for (int c = 0; c < 8; ++c) {
      uint4 u = *(const uint4*)&smem[cr * 136 + half * 64 + c * 8];
      *(uint4*)&vT[dbase + c * 8] = u;
    }
  } else {
    unsigned short* dst = qk + (size_t)z * M * D;
    const float* bias = z == 0 ? sq : sk;
    const float post = z == 0 ? QSCALE : 1.0f;
    // stage [row][col] into smem, then fully-coalesced 16B stores
#pragma unroll
    for (int i = 0; i < 4; ++i)
#pragma unroll
      for (int j = 0; j < 4; ++j)
#pragma unroll
        for (int r = 0; r < 4; ++r) {
          int rr = 64 * wm + 16 * i + 4 * lq + r;
          int cc = 64 * wn + 16 * j + lm;
          float v = (acc[i][j][r] + bias[((m0 + rr) >> 11) * D + n0 + cc]) * post;
          smem[rr * 136 + cc] = f2bf(v);
        }
    __syncthreads();
    const int row = t >> 1, half = t & 1;
    const int bb = m0 >> 11, ll = (m0 & (L - 1)) + row;
    const int h0 = (n0 >> 6) + half;
    size_t dbase = ((size_t)(bb * H + h0) * L + ll) * HD;
#pragma unroll
    for (int c = 0; c < 8; ++c) {
      uint4 u = *(const uint4*)&smem[row * 136 + half * 64 + c * 8];
      *(uint4*)&dst[dbase + c * 8] = u;
    }
  }
}

// ---------------- flash attention (BK=128, register P, dbuf) ----------
// grid 512 XCD-swizzled; block 512 = 8 waves. Wave-pair key-split:
// wave w owns q-rows 32*(w&3)..+31 and 64 keys (2 groups of 32) of each
// 128-key tile. PV uses full-width mfma_f32_16x16x32_bf16 over 32-key
// groups via the QK^T A-operand K-row REMAP (see krow0/krow1).
// Row-sums via ones-column MFMA (same truncated bf16 p-values as PV ->
// truncation bias cancels in the ratio). s_setprio(1) wraps MFMA clusters.
// Mask bytes are loaded BEFORE the prefetch DMAs so the ballot's vmcnt wait
// does not drain the prefetch (FIFO vmcnt: mask loads are the oldest).
__global__ __launch_bounds__(512, 4) void attn_kernel(
    const unsigned short* __restrict__ q_hm, const unsigned short* __restrict__ k_hm,
    const unsigned short* __restrict__ vT, const unsigned char* __restrict__ mask,
    unsigned short* __restrict__ ctx) {
  __shared__ __align__(16) unsigned short smem[40960];  // 80 KB pool
  unsigned short* Qs  = smem;                // 128*64   (16 KB)
  unsigned short* Ksb = smem + 8192;         // 2*128*64 (32 KB) [buf][key][feat]
  unsigned short* Vtb = smem + 24576;        // 2*64*128 (32 KB) [buf][feat][key]
  const int bx = blockIdx.x;
  const int rest = bx >> 3;
  const int bhid = (bx & 7) + 8 * (rest >> 4);
  const int q0 = (rest & 15) * 128;
  const int h = bhid & 15, b = bhid >> 4;
  const size_t bh = (size_t)(b * H + h);
  const unsigned short* qp = q_hm + bh * L * HD;
  const unsigned short* kp = k_hm + bh * L * HD;
  const unsigned short* vp = vT + bh * HD * L;
  const int t = threadIdx.x, l = t & 63, w = t >> 6;
  const int wq = w & 3, wj = w >> 2;               // q-row group, key half
  const int lm = l & 15, lq = l >> 4;
  const int fsw = ((t & 7) ^ ((t >> 3) & 7)) * 8;  // 8-chunk swizzle (64-wide rows)
  const int swm = lm & 7;
  const int srow = t >> 3;                         // 0..63
  const int vs = t & 15, vr = t >> 4;              // V staging: slot, row (0..31)
  const int vcsrc = ((vs & 8) | ((vs & 7) ^ (vr & 7))) * 8;  // 16-chunk swizzle
  // K=32 A-layout key-row remap (see header comment)
  const int krow0 = 8 * (lm >> 2) + 4 * ((lm >> 2) & 1) + (lm & 3);
  const int ks0 = krow0 & 7;
  const int krow1 = krow0 ^ 4;
  const int ks1 = ks0 ^ 4;
  const bf16x8 vones = {(short)0x3F80, (short)0x3F80, (short)0x3F80, (short)0x3F80,
                        (short)0x3F80, (short)0x3F80, (short)0x3F80, (short)0x3F80};

  // stage Q + first K/V tile (512 threads: 2 rounds each)
#pragma unroll
  for (int c = 0; c < 2; ++c) {
    gload_lds16(&qp[(size_t)(q0 + 64 * c + srow) * HD + fsw], &Qs[(64 * c + 8 * w) * 64]);
    gload_lds16(&kp[(size_t)(64 * c + srow) * HD + fsw], &Ksb[(64 * c + 8 * w) * 64]);
    gload_lds16(&vp[(size_t)(32 * c + vr) * L + vcsrc], &Vtb[(32 * c + 4 * w) * 128]);
  }
  __syncthreads();
  bf16x8 qf[2][2];
#pragma unroll
  for (int i = 0; i < 2; ++i)
#pragma unroll
    for (int kk = 0; kk < 2; ++kk)
      qf[i][kk] = *(const bf16x8*)&Qs[(wq * 32 + 16 * i + lm) * 64 + ((kk * 4 + lq) ^ swm) * 8];

  f32x4 ot[2][4] = {};   // O[qrow=32wq+16i+4lq+r][feat=16jf+lm], this wave's key-half
  f32x4 ot1[2] = {};     // row-sums (ones-column): lane rows 4lq+r (lm duplicated)

  for (int kt = 0; kt < L / 128; ++kt) {
    const int cur = kt & 1;
    const unsigned short* Kc = Ksb + cur * 8192;
    const unsigned short* Vc = Vtb + cur * 8192;
    // mask bytes FIRST (oldest vmcnt entries); each wave needs only its half
    unsigned char mby = mask[b * L + kt * 128 + 64 * wj + l];
    if (kt + 1 < L / 128) {
      const int nk0 = (kt + 1) * 128;
      unsigned short* Kd = Ksb + (cur ^ 1) * 8192;
      unsigned short* Vd = Vtb + (cur ^ 1) * 8192;
#pragma unroll
      for (int c = 0; c < 2; ++c) {
        gload_lds16(&kp[(size_t)(nk0 + 64 * c + srow) * HD + fsw], &Kd[(64 * c + 8 * w) * 64]);
        gload_lds16(&vp[(size_t)(32 * c + vr) * L + nk0 + vcsrc], &Vd[(32 * c + 4 * w) * 128]);
      }
    }
    unsigned long long mb = __ballot(mby != 0);

#pragma unroll
    for (int g = 0; g < 2; ++g) {
      const int gg = 2 * wj + g;            // 32-key group within 128-key tile
      const unsigned short* Kg = Kc + 32 * gg * 64;
      // remapped K fragments: rows krow0 (->j per lq parity) and krow1
      bf16x8 ka0 = *(const bf16x8*)&Kg[krow0 * 64 + ((0 + lq) ^ ks0) * 8];
      bf16x8 ka1 = *(const bf16x8*)&Kg[krow0 * 64 + ((4 + lq) ^ ks0) * 8];
      bf16x8 kb0 = *(const bf16x8*)&Kg[krow1 * 64 + ((0 + lq) ^ ks1) * 8];
      bf16x8 kb1 = *(const bf16x8*)&Kg[krow1 * 64 + ((4 + lq) ^ ks1) * 8];
      f32x4 stA[2], stB[2];
      __builtin_amdgcn_s_setprio(1);
#pragma unroll
      for (int i = 0; i < 2; ++i) {
        f32x4 a = {};
        a = __builtin_amdgcn_mfma_f32_16x16x32_bf16(ka0, qf[i][0], a, 0, 0, 0);
        a = __builtin_amdgcn_mfma_f32_16x16x32_bf16(ka1, qf[i][1], a, 0, 0, 0);
        stA[i] = a;
        f32x4 bq = {};
        bq = __builtin_amdgcn_mfma_f32_16x16x32_bf16(kb0, qf[i][0], bq, 0, 0, 0);
        bq = __builtin_amdgcn_mfma_f32_16x16x32_bf16(kb1, qf[i][1], bq, 0, 0, 0);
        stB[i] = bq;
      }
      __builtin_amdgcn_s_setprio(0);
      if (mb) {  // wave-uniform; all-false mask skips this
        // stA lane keys: 32g + 8lq + 4(lq&1) + r; stB: ^4
        const int shA = 32 * g + 8 * lq + 4 * (lq & 1);
        unsigned bitsA = (unsigned)(mb >> shA);
        unsigned bitsB = (unsigned)(mb >> (shA ^ 4));
#pragma unroll
        for (int i = 0; i < 2; ++i)
#pragma unroll
          for (int r = 0; r < 4; ++r) {
            if ((bitsA >> r) & 1u) stA[i][r] = -1e30f;
            if ((bitsB >> r) & 1u) stB[i][r] = -1e30f;
          }
      }
      // p = exp2(s); build K=32 A-fragment (lq parity selects quad order)
      union { uint4 q; bf16x8 v; } pa[2];
      const bool sw = (lq & 1) != 0;
#pragma unroll
      for (int i = 0; i < 2; ++i) {
        float eA[4], eB[4];
#pragma unroll
        for (int r = 0; r < 4; ++r) {
          eA[r] = __builtin_amdgcn_exp2f(stA[i][r]);
          eB[r] = __builtin_amdgcn_exp2f(stB[i][r]);
        }
        unsigned a01 = pack2bf_trunc(eA[0], eA[1]);
        unsigned a23 = pack2bf_trunc(eA[2], eA[3]);
        unsigned b01 = pack2bf_trunc(eB[0], eB[1]);
        unsigned b23 = pack2bf_trunc(eB[2], eB[3]);
        pa[i].q.x = sw ? b01 : a01;
        pa[i].q.y = sw ? b23 : a23;
        pa[i].q.z = sw ? a01 : b01;
        pa[i].q.w = sw ? a23 : b23;
      }
      // O += P@V for this 32-key group (b128 V^T reads, K=32 MFMA);
      // ones-column MFMA accumulates row-sums into ot1 (C-layout rows).
      const int kc = 4 * gg + lq;                    // 8-key chunk index
      const int slot = (kc & 8) | ((kc & 7) ^ swm);
      __builtin_amdgcn_s_setprio(1);
#pragma unroll
      for (int jf = 0; jf < 4; ++jf) {
        bf16x8 vb = *(const bf16x8*)&Vc[(16 * jf + lm) * 128 + slot * 8];
#pragma unroll
        for (int i = 0; i < 2; ++i)
          ot[i][jf] = __builtin_amdgcn_mfma_f32_16x16x32_bf16(pa[i].v, vb, ot[i][jf], 0, 0, 0);
      }
#pragma unroll
      for (int i = 0; i < 2; ++i)
        ot1[i] = __builtin_amdgcn_mfma_f32_16x16x32_bf16(pa[i].v, vones, ot1[i], 0, 0, 0);
      __builtin_amdgcn_s_setprio(0);
    }
    __syncthreads();
  }

  // ---- epilogue: combine wave-pair partials, normalize, store ----
  // All K/V/Q LDS is dead past the final loop barrier; carve scratch:
  float* Obuf = (float*)smem;                 // [64 cols][stride 132] f32, 33.8 KB
  unsigned short* Es = smem + 20480;          // byte 40960; stride-72 rows, 18.4 KB
  float* Sred = (float*)(smem + 35840);       // byte 71680; 8*32 floats

  // publish C-layout row sums (rows 32wq+16i+4lq+r); lm lanes duplicate
  if (lm == 0) {
#pragma unroll
    for (int i = 0; i < 2; ++i)
#pragma unroll
      for (int r = 0; r < 4; ++r)
        Sred[w * 32 + 16 * i + 4 * lq + r] = ot1[i][r];
  }
  if (wj) {
    // upper waves park raw O partials (col-major, r contiguous -> f32x4)
#pragma unroll
    for (int i = 0; i < 2; ++i)
#pragma unroll
      for (int jf = 0; jf < 4; ++jf)
        *(f32x4*)&Obuf[(16 * jf + lm) * 132 + wq * 32 + 16 * i + 4 * lq] = ot[i][jf];
  }
  __syncthreads();
  if (!wj) {
    float rlq[2][4];
#pragma unroll
    for (int i = 0; i < 2; ++i)
#pragma unroll
      for (int r = 0; r < 4; ++r)
        rlq[i][r] = 1.0f / (ot1[i][r] + Sred[(w + 4) * 32 + 16 * i + 4 * lq + r]);
#pragma unroll
    for (int i = 0; i < 2; ++i)
#pragma unroll
      for (int jf = 0; jf < 4; ++jf) {
        f32x4 po = *(const f32x4*)&Obuf[(16 * jf + lm) * 132 + wq * 32 + 16 * i + 4 * lq];
        ot[i][jf] += po;
      }
    // O rows -> Es (stride 72) -> coalesced 16B stores.
    // Safe without barrier: each wave touches only its own 32 rows.
#pragma unroll
    for (int i = 0; i < 2; ++i)
#pragma unroll
      for (int jf = 0; jf < 4; ++jf)
#pragma unroll
        for (int r = 0; r < 4; ++r)
          Es[(wq * 32 + 16 * i + 4 * lq + r) * 72 + 16 * jf + lm] =
              f2bf(ot[i][jf][r] * rlq[i][r]);
    int row = l >> 1, half = l & 1;
    size_t obase = ((size_t)(b * L + q0 + wq * 32 + row)) * D + h * HD + half * 32;
#pragma unroll
    for (int c = 0; c < 4; ++c) {
      uint4 u = *(const uint4*)&Es[(wq * 32 + row) * 72 + half * 32 + c * 8];
      *(uint4*)&ctx[obase + c * 8] = u;
    }
  }
}

// ---------------- output projection GEMM (BK=64, 2-phase dbuf) ----------
// out = ctx@Wo + bo. XCD-chunked block swizzle (bijective: 512 = 8 x 64)
// + 2-phase gload_lds prefetch (grid 512 = exactly 2 blocks/CU).
__global__ __launch_bounds__(256) void outgemm_kernel(
    const unsigned short* __restrict__ ctx, const unsigned short* __restrict__ WoT,
    const float* __restrict__ bo, float* __restrict__ out) {
  __shared__ __align__(16) unsigned short smem[24576];  // 48 KB: 2x(As+Bs)
  const int lin = blockIdx.x + 8 * blockIdx.y;
  const int nlin = (lin & 7) * 64 + (lin >> 3);   // XCD chunk remap
  const int m0 = (nlin >> 3) * 64, n0 = (nlin & 7) * 128;
  const int t = threadIdx.x, l = t & 63, w = t >> 6;
  const int wm = w >> 1, wn = w & 1;
  const int lm = l & 15, lq = l >> 4;
  const int srow8 = t >> 3;
  const int fsw = ((t & 7) ^ ((t >> 3) & 7)) * 8;
  const int swm = lm & 7;

  auto stage = [&](int kt, int bsel) {
    const int kb = kt * 64;
    unsigned short* As = smem + bsel * 12288;
    unsigned short* Bs = As + 4096;
#pragma unroll
    for (int c = 0; c < 2; ++c)
      gload_lds16(&ctx[(size_t)(m0 + 32 * c + srow8) * D + kb + fsw],
                  &As[(32 * c + 8 * w) * 64]);
#pragma unroll
    for (int c = 0; c < 4; ++c)
      gload_lds16(&WoT[(size_t)(n0 + 32 * c + srow8) * D + kb + fsw],
                  &Bs[(32 * c + 8 * w) * 64]);
  };

  f32x4 acc[2][4] = {};
  stage(0, 0);
  __syncthreads();
  for (int kt = 0; kt < D / 64; ++kt) {
    const int cur = kt & 1;
    if (kt + 1 < D / 64) stage(kt + 1, cur ^ 1);
    const unsigned short* As = smem + cur * 12288;
    const unsigned short* Bs = As + 4096;
#pragma unroll
    for (int kk = 0; kk < 2; ++kk) {
      bf16x8 af[2], bf[4];
#pragma unroll
      for (int i = 0; i < 2; ++i)
        af[i] = *(const bf16x8*)&As[(32 * wm + 16 * i + lm) * 64 + ((kk * 4 + lq) ^ swm) * 8];
#pragma unroll
      for (int j = 0; j < 4; ++j)
        bf[j] = *(const bf16x8*)&Bs[(64 * wn + 16 * j + lm) * 64 + ((kk * 4 + lq) ^ swm) * 8];
#pragma unroll
      for (int i = 0; i < 2; ++i)
#pragma unroll
        for (int j = 0; j < 4; ++j)
          acc[i][j] = __builtin_amdgcn_mfma_f32_16x16x32_bf16(af[i], bf[j], acc[i][j], 0, 0, 0);
    }
    __syncthreads();
  }
#pragma unroll
  for (int i = 0; i < 2; ++i)
#pragma unroll
    for (int j = 0; j < 4; ++j)
#pragma unroll
      for (int r = 0; r < 4; ++r) {
        int grow = m0 + 32 * wm + 16 * i + lq * 4 + r;
        int gcol = n0 + 64 * wn + 16 * j + lm;
        out[(size_t)grow * D + gcol] = acc[i][j][r] + bo[gcol];
      }
}

extern "C" void kernel_launch(void* const* d_in, const int* in_sizes, int n_in,
                              void* d_out, int out_size, void* d_ws, size_t ws_size,
                              hipStream_t stream) {
  const float* x    = (const float*)d_in[0];
  const float* subj = (const float*)d_in[1];
  const unsigned char* mask = (const unsigned char*)d_in[2];
  const float* Wq = (const float*)d_in[3];
  const float* Wk = (const float*)d_in[4];
  const float* Wv = (const float*)d_in[5];
  const float* Wo = (const float*)d_in[6];
  const float* bo = (const float*)d_in[7];
  const float* Wsq = (const float*)d_in[8];
  const float* bsq = (const float*)d_in[9];
  const float* Wsk = (const float*)d_in[10];
  const float* bsk = (const float*)d_in[11];
  float* out = (float*)d_out;
  char* ws = (char*)d_ws;

  // workspace layout (bytes)
  unsigned short* xb  = (unsigned short*)(ws);                    // 8 MB
  unsigned short* WT4 = (unsigned short*)(ws + (8ull  << 20));    // 8 MB
  unsigned short* qk  = (unsigned short*)(ws + (16ull << 20));    // 16 MB (q,k)
  unsigned short* ctx = (unsigned short*)(ws + (32ull << 20));    // 8 MB
  unsigned short* vT  = (unsigned short*)(ws + (40ull << 20));    // 8 MB
  float* sq = (float*)(ws + (48ull << 20));                       // 8 KB
  float* sk = sq + B * D;

  hipLaunchKernelGGL(prep_kernel, dim3(3088), dim3(256), 0, stream,
                     Wq, Wk, Wv, Wo, x, subj, Wsq, bsq, Wsk, bsk, WT4, xb, sq, sk);
  hipLaunchKernelGGL(proj_kernel, dim3(8, 32, 3), dim3(256), 0, stream,
                     xb, WT4, sq, sk, qk, vT);
  hipLaunchKernelGGL(attn_kernel, dim3(512), dim3(512), 0, stream,
                     qk, qk + (size_t)M * D, vT, mask, ctx);
  hipLaunchKernelGGL(outgemm_kernel, dim3(8, 64, 1), dim3(256), 0, stream, ctx,
                     WT4 + 3ull * D * D, bo, out);
}

// Round 14
// 188.211 us; speedup vs baseline: 1.4608x; 1.0048x over previous
//
#include <hip/hip_runtime.h>
#include <hip/hip_bf16.h>
#include <math.h>

#define DEV __device__ __forceinline__

typedef short bf16x8 __attribute__((ext_vector_type(8)));
typedef short bf16x4 __attribute__((ext_vector_type(4)));
typedef float f32x4 __attribute__((ext_vector_type(4)));

static constexpr int D  = 1024;
static constexpr int H  = 16;
static constexpr int HD = 64;
static constexpr int DS = 64;
static constexpr int B  = 2;
static constexpr int L  = 2048;
static constexpr int M  = B * L;   // 4096

// softmax scale * log2(e), folded into q at projection time (exp2-based
// softmax, no max subtraction: scores bounded far below exp2 overflow;
// masked scores (-1e30) give exp2 -> 0 exactly).
static constexpr float QSCALE = 0.18033688011112042f; // 0.125 * log2(e)

DEV unsigned short f2bf(float f) {
  union { float f; unsigned u; } x; x.f = f;
  unsigned r = (x.u + 0x7FFFu + ((x.u >> 16) & 1u)) >> 16;
  return (unsigned short)r;
}

DEV unsigned pack2bf(float a, float b) {
  return (unsigned)f2bf(a) | ((unsigned)f2bf(b) << 16);
}

// truncation pack (P only: truncation bias cancels between Sum(p*v) and Sum(p))
// single v_perm_b32: bytes [ua.b2, ua.b3, ub.b2, ub.b3]
DEV unsigned pack2bf_trunc(float a, float b) {
  union { float f; unsigned u; } ua{a}, ub{b};
  return __builtin_amdgcn_perm(ub.u, ua.u, 0x07060302u);
}

// async global->LDS, 16B per lane; LDS dest = wave-uniform base + 16*lane.
DEV void gload_lds16(const void* g, void* l) {
  __builtin_amdgcn_global_load_lds(
      (const __attribute__((address_space(1))) unsigned int*)g,
      (__attribute__((address_space(3))) unsigned int*)l, 16, 0, 0);
}

// ---------------- merged preprocessing ----------------
// blocks [0,1024): W transpose+bf16 (vectorized: float4 reads, ushort4
// transposed stores); [1024,3072): x->bf16; [3072,3088): sq/sk
__global__ __launch_bounds__(256) void prep_kernel(
    const float* __restrict__ Wq, const float* __restrict__ Wk,
    const float* __restrict__ Wv, const float* __restrict__ Wo,
    const float* __restrict__ x, const float* __restrict__ subj,
    const float* __restrict__ Wsq, const float* __restrict__ bsq,
    const float* __restrict__ Wsk, const float* __restrict__ bsk,
    unsigned short* __restrict__ WT4, unsigned short* __restrict__ xb,
    float* __restrict__ sq, float* __restrict__ sk) {
  __shared__ float tile[64][65];
  const int blk = blockIdx.x, t = threadIdx.x;
  if (blk < 1024) {
    const int z = blk >> 8, idx = blk & 255;
    const float* W = z == 0 ? Wq : z == 1 ? Wk : z == 2 ? Wv : Wo;
    unsigned short* dst = WT4 + (size_t)z * D * D;
    const int n0 = (idx & 15) * 64, k0 = (idx >> 4) * 64;
    const int c4 = (t & 15) * 4;   // 4-col group
    const int r16 = t >> 4;        // 0..15
#pragma unroll
    for (int rr = 0; rr < 4; ++rr) {
      int row = r16 + rr * 16;
      float4 v = *(const float4*)&W[(size_t)(k0 + row) * D + n0 + c4];
      tile[row][c4 + 0] = v.x;
      tile[row][c4 + 1] = v.y;
      tile[row][c4 + 2] = v.z;
      tile[row][c4 + 3] = v.w;
    }
    __syncthreads();
#pragma unroll
    for (int rr = 0; rr < 4; ++rr) {
      int nrow = r16 + rr * 16;
      ushort4 u;
      u.x = f2bf(tile[c4 + 0][nrow]);
      u.y = f2bf(tile[c4 + 1][nrow]);
      u.z = f2bf(tile[c4 + 2][nrow]);
      u.w = f2bf(tile[c4 + 3][nrow]);
      *(ushort4*)&dst[(size_t)(n0 + nrow) * D + k0 + c4] = u;
    }
  } else if (blk < 3072) {
    size_t g = (size_t)(blk - 1024) * 256 + t;
    const float4* xf = (const float4*)x;
    float4 a = xf[2 * g], b = xf[2 * g + 1];
    union { unsigned short s[8]; uint4 v; } o;
    o.s[0] = f2bf(a.x); o.s[1] = f2bf(a.y); o.s[2] = f2bf(a.z); o.s[3] = f2bf(a.w);
    o.s[4] = f2bf(b.x); o.s[5] = f2bf(b.y); o.s[6] = f2bf(b.z); o.s[7] = f2bf(b.w);
    ((uint4*)xb)[g] = o.v;
  } else {
    int g = (blk - 3072) * 256 + t;  // [0, 4096)
    int ty = g >> 11, b = (g >> 10) & 1, n = g & 1023;
    const float* W = ty ? Wsk : Wsq;
    const float* bias = ty ? bsk : bsq;
    float s = bias[n];
#pragma unroll 8
    for (int d = 0; d < DS; ++d) s += subj[b * DS + d] * W[d * D + n];
    (ty ? sk : sq)[b * D + n] = s;
  }
}

// ---------------- fused QKV projection GEMM (z-FUSED, BK=64 dbuf) -------
// One block computes q, k AND v for a 128(m) x 64(n=one head) tile: the
// shared A-operand (xb) is staged ONCE per K-step for 48 MFMAs (3 z x 16)
// instead of per-z (r13 measured: per-step cost ~4300 cyc is invariant to
// staging scheme -- so amortize MORE WORK per step, not a better wait).
// Grid 512 = exactly 1 dispatch round (old 768 = 1.5 rounds serialized).
// Per buf: As 128x64 (16 KB) + 3x Bs 64x64 (24 KB) = 40 KB; dbuf 80 KB ->
// 2 blocks/CU (same occupancy as r13). acc = 3x2x4 f32x4 = 96 VGPR,
// statically indexed (standard GEMM acc pattern; NOT r7/r8's cross-barrier
// reg-staging that spilled). 2D XCD chunk (8m x 8n per XCD): working set
// ~2 MB xb + 3 MB W per XCD stays near-L2. Three sequential epilogues
// (q, k: bias+coalesced stores; v: fused transpose) reuse the LDS pool.
__global__ __launch_bounds__(256) void proj_kernel(
    const unsigned short* __restrict__ xb, const unsigned short* __restrict__ WT3,
    const float* __restrict__ sq, const float* __restrict__ sk,
    unsigned short* __restrict__ qk, unsigned short* __restrict__ vT) {
  __shared__ __align__(16) unsigned short smem[40960];  // 80 KB: 2 bufs x 40 KB
  // buf layout (elements): As [0,8192); Bs z=0 [8192,12288); z=1
  // [12288,16384); z=2 [16384,20480). buf1 at +20480.
  const int lin = blockIdx.x + 8 * blockIdx.y;     // 0..511
  const int x8 = lin & 7, c = lin >> 3;            // XCD, chunk idx 0..63
  const int mt = (x8 & 3) * 8 + (c >> 3);          // m-tile 0..31
  const int nt = (x8 >> 2) * 8 + (c & 7);          // n-tile (= head) 0..15
  const int m0 = mt * 128, n0 = nt * 64;
  const int t = threadIdx.x, l = t & 63, w = t >> 6;
  const int lm = l & 15, lq = l >> 4;
  const int srow8 = t >> 3;
  const int fsw = ((t & 7) ^ ((t >> 3) & 7)) * 8;
  const int swm = lm & 7;

  auto stage = [&](int kt, int bsel) {
    const int kb = kt * 64;
    unsigned short* As = smem + bsel * 20480;
    unsigned short* Bs = As + 8192;
#pragma unroll
    for (int cc = 0; cc < 4; ++cc)
      gload_lds16(&xb[(size_t)(m0 + 32 * cc + srow8) * D + kb + fsw],
                  &As[(32 * cc + 8 * w) * 64]);
#pragma unroll
    for (int z = 0; z < 3; ++z)
#pragma unroll
      for (int cc = 0; cc < 2; ++cc)
        gload_lds16(&WT3[(size_t)z * D * D + (size_t)(n0 + 32 * cc + srow8) * D + kb + fsw],
                    &Bs[z * 4096 + (32 * cc + 8 * w) * 64]);
  };

  f32x4 acc[3][2][4] = {};
  stage(0, 0);
  __syncthreads();
  for (int kt = 0; kt < D / 64; ++kt) {
    const int cur = kt & 1;
    if (kt + 1 < D / 64) stage(kt + 1, cur ^ 1);
    const unsigned short* As = smem + cur * 20480;
    const unsigned short* Bs = As + 8192;
#pragma unroll
    for (int kk = 0; kk < 2; ++kk) {
      bf16x8 af[2];
#pragma unroll
      for (int i = 0; i < 2; ++i)
        af[i] = *(const bf16x8*)&As[(32 * w + 16 * i + lm) * 64 + ((kk * 4 + lq) ^ swm) * 8];
#pragma unroll
      for (int z = 0; z < 3; ++z)
#pragma unroll
        for (int j = 0; j < 4; ++j) {
          bf16x8 bfj = *(const bf16x8*)&Bs[z * 4096 + (16 * j + lm) * 64 + ((kk * 4 + lq) ^ swm) * 8];
#pragma unroll
          for (int i = 0; i < 2; ++i)
            acc[z][i][j] = __builtin_amdgcn_mfma_f32_16x16x32_bf16(af[i], bfj, acc[z][i][j], 0, 0, 0);
        }
    }
    __syncthreads();  // vmcnt(0): prefetch (issued pre-compute) has landed
  }

  const int bb = m0 >> 11;          // batch
  const int l0 = m0 & (L - 1);      // seq offset
  const int h0 = nt;                // head (n0 = 64*nt)

  // ---- q/k epilogues: bias + QSCALE, stride-72 staging, coalesced stores
#pragma unroll
  for (int z = 0; z < 2; ++z) {
    const float* bias = z == 0 ? sq : sk;
    const float post = z == 0 ? QSCALE : 1.0f;
    unsigned short* dst = qk + (size_t)z * M * D;
#pragma unroll
    for (int i = 0; i < 2; ++i)
#pragma unroll
      for (int j = 0; j < 4; ++j)
#pragma unroll
        for (int r = 0; r < 4; ++r) {
          int rr = 32 * w + 16 * i + 4 * lq + r;
          int cc = 16 * j + lm;
          float v = (acc[z][i][j][r] + bias[bb * D + n0 + cc]) * post;
          smem[rr * 72 + cc] = f2bf(v);
        }
    __syncthreads();
    const int row = t >> 1, half = t & 1;
    size_t dbase = ((size_t)(bb * H + h0) * L + l0 + row) * HD + half * 32;
#pragma unroll
    for (int cq = 0; cq < 4; ++cq) {
      uint4 u = *(const uint4*)&smem[row * 72 + half * 32 + cq * 8];
      *(uint4*)&dst[dbase + cq * 8] = u;
    }
    __syncthreads();   // all reads done before next epilogue overwrites
  }

  // ---- v epilogue: transpose through smem (stride 136) -> vT[bh][hd][l]
#pragma unroll
  for (int i = 0; i < 2; ++i)
#pragma unroll
    for (int j = 0; j < 4; ++j) {
      int cr = 16 * j + lm;                 // hd 0..63
      int rr = 32 * w + 16 * i + 4 * lq;    // l-row 0..124
      uint2 u;
      u.x = pack2bf(acc[2][i][j][0], acc[2][i][j][1]);
      u.y = pack2bf(acc[2][i][j][2], acc[2][i][j][3]);
      *(uint2*)&smem[cr * 136 + rr] = u;
    }
  __syncthreads();
  {
    const int cr = t >> 2, quarter = t & 3;   // hd row, 32-el quarter
    size_t dbase = ((size_t)(bb * H + h0) * HD + cr) * L + l0 + quarter * 32;
#pragma unroll
    for (int cq = 0; cq < 4; ++cq) {
      uint4 u = *(const uint4*)&smem[cr * 136 + quarter * 32 + cq * 8];
      *(uint4*)&vT[dbase + cq * 8] = u;
    }
  }
}

// ---------------- flash attention (BK=128, register P, dbuf) ----------
// grid 512 XCD-swizzled; block 512 = 8 waves. Wave-pair key-split:
// wave w owns q-rows 32*(w&3)..+31 and 64 keys (2 groups of 32) of each
// 128-key tile. PV uses full-width mfma_f32_16x16x32_bf16 over 32-key
// groups via the QK^T A-operand K-row REMAP (see krow0/krow1).
// Row-sums via ones-column MFMA (same truncated bf16 p-values as PV ->
// truncation bias cancels in the ratio). s_setprio(1) wraps MFMA clusters.
// Mask bytes are loaded BEFORE the prefetch DMAs so the ballot's vmcnt wait
// does not drain the prefetch (FIFO vmcnt: mask loads are the oldest).
__global__ __launch_bounds__(512, 4) void attn_kernel(
    const unsigned short* __restrict__ q_hm, const unsigned short* __restrict__ k_hm,
    const unsigned short* __restrict__ vT, const unsigned char* __restrict__ mask,
    unsigned short* __restrict__ ctx) {
  __shared__ __align__(16) unsigned short smem[40960];  // 80 KB pool
  unsigned short* Qs  = smem;                // 128*64   (16 KB)
  unsigned short* Ksb = smem + 8192;         // 2*128*64 (32 KB) [buf][key][feat]
  unsigned short* Vtb = smem + 24576;        // 2*64*128 (32 KB) [buf][feat][key]
  const int bx = blockIdx.x;
  const int rest = bx >> 3;
  const int bhid = (bx & 7) + 8 * (rest >> 4);
  const int q0 = (rest & 15) * 128;
  const int h = bhid & 15, b = bhid >> 4;
  const size_t bh = (size_t)(b * H + h);
  const unsigned short* qp = q_hm + bh * L * HD;
  const unsigned short* kp = k_hm + bh * L * HD;
  const unsigned short* vp = vT + bh * HD * L;
  const int t = threadIdx.x, l = t & 63, w = t >> 6;
  const int wq = w & 3, wj = w >> 2;               // q-row group, key half
  const int lm = l & 15, lq = l >> 4;
  const int fsw = ((t & 7) ^ ((t >> 3) & 7)) * 8;  // 8-chunk swizzle (64-wide rows)
  const int swm = lm & 7;
  const int srow = t >> 3;                         // 0..63
  const int vs = t & 15, vr = t >> 4;              // V staging: slot, row (0..31)
  const int vcsrc = ((vs & 8) | ((vs & 7) ^ (vr & 7))) * 8;  // 16-chunk swizzle
  // K=32 A-layout key-row remap (see header comment)
  const int krow0 = 8 * (lm >> 2) + 4 * ((lm >> 2) & 1) + (lm & 3);
  const int ks0 = krow0 & 7;
  const int krow1 = krow0 ^ 4;
  const int ks1 = ks0 ^ 4;
  const bf16x8 vones = {(short)0x3F80, (short)0x3F80, (short)0x3F80, (short)0x3F80,
                        (short)0x3F80, (short)0x3F80, (short)0x3F80, (short)0x3F80};

  // stage Q + first K/V tile (512 threads: 2 rounds each)
#pragma unroll
  for (int c = 0; c < 2; ++c) {
    gload_lds16(&qp[(size_t)(q0 + 64 * c + srow) * HD + fsw], &Qs[(64 * c + 8 * w) * 64]);
    gload_lds16(&kp[(size_t)(64 * c + srow) * HD + fsw], &Ksb[(64 * c + 8 * w) * 64]);
    gload_lds16(&vp[(size_t)(32 * c + vr) * L + vcsrc], &Vtb[(32 * c + 4 * w) * 128]);
  }
  __syncthreads();
  bf16x8 qf[2][2];
#pragma unroll
  for (int i = 0; i < 2; ++i)
#pragma unroll
    for (int kk = 0; kk < 2; ++kk)
      qf[i][kk] = *(const bf16x8*)&Qs[(wq * 32 + 16 * i + lm) * 64 + ((kk * 4 + lq) ^ swm) * 8];

  f32x4 ot[2][4] = {};   // O[qrow=32wq+16i+4lq+r][feat=16jf+lm], this wave's key-half
  f32x4 ot1[2] = {};     // row-sums (ones-column): lane rows 4lq+r (lm duplicated)

  for (int kt = 0; kt < L / 128; ++kt) {
    const int cur = kt & 1;
    const unsigned short* Kc = Ksb + cur * 8192;
    const unsigned short* Vc = Vtb + cur * 8192;
    // mask bytes FIRST (oldest vmcnt entries); each wave needs only its half
    unsigned char mby = mask[b * L + kt * 128 + 64 * wj + l];
    if (kt + 1 < L / 128) {
      const int nk0 = (kt + 1) * 128;
      unsigned short* Kd = Ksb + (cur ^ 1) * 8192;
      unsigned short* Vd = Vtb + (cur ^ 1) * 8192;
#pragma unroll
      for (int c = 0; c < 2; ++c) {
        gload_lds16(&kp[(size_t)(nk0 + 64 * c + srow) * HD + fsw], &Kd[(64 * c + 8 * w) * 64]);
        gload_lds16(&vp[(size_t)(32 * c + vr) * L + nk0 + vcsrc], &Vd[(32 * c + 4 * w) * 128]);
      }
    }
    unsigned long long mb = __ballot(mby != 0);

#pragma unroll
    for (int g = 0; g < 2; ++g) {
      const int gg = 2 * wj + g;            // 32-key group within 128-key tile
      const unsigned short* Kg = Kc + 32 * gg * 64;
      // remapped K fragments: rows krow0 (->j per lq parity) and krow1
      bf16x8 ka0 = *(const bf16x8*)&Kg[krow0 * 64 + ((0 + lq) ^ ks0) * 8];
      bf16x8 ka1 = *(const bf16x8*)&Kg[krow0 * 64 + ((4 + lq) ^ ks0) * 8];
      bf16x8 kb0 = *(const bf16x8*)&Kg[krow1 * 64 + ((0 + lq) ^ ks1) * 8];
      bf16x8 kb1 = *(const bf16x8*)&Kg[krow1 * 64 + ((4 + lq) ^ ks1) * 8];
      f32x4 stA[2], stB[2];
      __builtin_amdgcn_s_setprio(1);
#pragma unroll
      for (int i = 0; i < 2; ++i) {
        f32x4 a = {};
        a = __builtin_amdgcn_mfma_f32_16x16x32_bf16(ka0, qf[i][0], a, 0, 0, 0);
        a = __builtin_amdgcn_mfma_f32_16x16x32_bf16(ka1, qf[i][1], a, 0, 0, 0);
        stA[i] = a;
        f32x4 bq = {};
        bq = __builtin_amdgcn_mfma_f32_16x16x32_bf16(kb0, qf[i][0], bq, 0, 0, 0);
        bq = __builtin_amdgcn_mfma_f32_16x16x32_bf16(kb1, qf[i][1], bq, 0, 0, 0);
        stB[i] = bq;
      }
      __builtin_amdgcn_s_setprio(0);
      if (mb) {  // wave-uniform; all-false mask skips this
        // stA lane keys: 32g + 8lq + 4(lq&1) + r; stB: ^4
        const int shA = 32 * g + 8 * lq + 4 * (lq & 1);
        unsigned bitsA = (unsigned)(mb >> shA);
        unsigned bitsB = (unsigned)(mb >> (shA ^ 4));
#pragma unroll
        for (int i = 0; i < 2; ++i)
#pragma unroll
          for (int r = 0; r < 4; ++r) {
            if ((bitsA >> r) & 1u) stA[i][r] = -1e30f;
            if ((bitsB >> r) & 1u) stB[i][r] = -1e30f;
          }
      }
      // p = exp2(s); build K=32 A-fragment (lq parity selects quad order)
      union { uint4 q; bf16x8 v; } pa[2];
      const bool sw = (lq & 1) != 0;
#pragma unroll
      for (int i = 0; i < 2; ++i) {
        float eA[4], eB[4];
#pragma unroll
        for (int r = 0; r < 4; ++r) {
          eA[r] = __builtin_amdgcn_exp2f(stA[i][r]);
          eB[r] = __builtin_amdgcn_exp2f(stB[i][r]);
        }
        unsigned a01 = pack2bf_trunc(eA[0], eA[1]);
        unsigned a23 = pack2bf_trunc(eA[2], eA[3]);
        unsigned b01 = pack2bf_trunc(eB[0], eB[1]);
        unsigned b23 = pack2bf_trunc(eB[2], eB[3]);
        pa[i].q.x = sw ? b01 : a01;
        pa[i].q.y = sw ? b23 : a23;
        pa[i].q.z = sw ? a01 : b01;
        pa[i].q.w = sw ? a23 : b23;
      }
      // O += P@V for this 32-key group (b128 V^T reads, K=32 MFMA);
      // ones-column MFMA accumulates row-sums into ot1 (C-layout rows).
      const int kc = 4 * gg + lq;                    // 8-key chunk index
      const int slot = (kc & 8) | ((kc & 7) ^ swm);
      __builtin_amdgcn_s_setprio(1);
#pragma unroll
      for (int jf = 0; jf < 4; ++jf) {
        bf16x8 vb = *(const bf16x8*)&Vc[(16 * jf + lm) * 128 + slot * 8];
#pragma unroll
        for (int i = 0; i < 2; ++i)
          ot[i][jf] = __builtin_amdgcn_mfma_f32_16x16x32_bf16(pa[i].v, vb, ot[i][jf], 0, 0, 0);
      }
#pragma unroll
      for (int i = 0; i < 2; ++i)
        ot1[i] = __builtin_amdgcn_mfma_f32_16x16x32_bf16(pa[i].v, vones, ot1[i], 0, 0, 0);
      __builtin_amdgcn_s_setprio(0);
    }
    __syncthreads();
  }

  // ---- epilogue: combine wave-pair partials, normalize, store ----
  // All K/V/Q LDS is dead past the final loop barrier; carve scratch:
  float* Obuf = (float*)smem;                 // [64 cols][stride 132] f32, 33.8 KB
  unsigned short* Es = smem + 20480;          // byte 40960; stride-72 rows, 18.4 KB
  float* Sred = (float*)(smem + 35840);       // byte 71680; 8*32 floats

  // publish C-layout row sums (rows 32wq+16i+4lq+r); lm lanes duplicate
  if (lm == 0) {
#pragma unroll
    for (int i = 0; i < 2; ++i)
#pragma unroll
      for (int r = 0; r < 4; ++r)
        Sred[w * 32 + 16 * i + 4 * lq + r] = ot1[i][r];
  }
  if (wj) {
    // upper waves park raw O partials (col-major, r contiguous -> f32x4)
#pragma unroll
    for (int i = 0; i < 2; ++i)
#pragma unroll
      for (int jf = 0; jf < 4; ++jf)
        *(f32x4*)&Obuf[(16 * jf + lm) * 132 + wq * 32 + 16 * i + 4 * lq] = ot[i][jf];
  }
  __syncthreads();
  if (!wj) {
    float rlq[2][4];
#pragma unroll
    for (int i = 0; i < 2; ++i)
#pragma unroll
      for (int r = 0; r < 4; ++r)
        rlq[i][r] = 1.0f / (ot1[i][r] + Sred[(w + 4) * 32 + 16 * i + 4 * lq + r]);
#pragma unroll
    for (int i = 0; i < 2; ++i)
#pragma unroll
      for (int jf = 0; jf < 4; ++jf) {
        f32x4 po = *(const f32x4*)&Obuf[(16 * jf + lm) * 132 + wq * 32 + 16 * i + 4 * lq];
        ot[i][jf] += po;
      }
    // O rows -> Es (stride 72) -> coalesced 16B stores.
    // Safe without barrier: each wave touches only its own 32 rows.
#pragma unroll
    for (int i = 0; i < 2; ++i)
#pragma unroll
      for (int jf = 0; jf < 4; ++jf)
#pragma unroll
        for (int r = 0; r < 4; ++r)
          Es[(wq * 32 + 16 * i + 4 * lq + r) * 72 + 16 * jf + lm] =
              f2bf(ot[i][jf][r] * rlq[i][r]);
    int row = l >> 1, half = l & 1;
    size_t obase = ((size_t)(b * L + q0 + wq * 32 + row)) * D + h * HD + half * 32;
#pragma unroll
    for (int c = 0; c < 4; ++c) {
      uint4 u = *(const uint4*)&Es[(wq * 32 + row) * 72 + half * 32 + c * 8];
      *(uint4*)&ctx[obase + c * 8] = u;
    }
  }
}

// ---------------- output projection GEMM (BK=64, 2-phase dbuf) ----------
// out = ctx@Wo + bo. XCD-chunked block swizzle (bijective: 512 = 8 x 64)
// + 2-phase gload_lds prefetch (grid 512 = exactly 2 blocks/CU).
__global__ __launch_bounds__(256) void outgemm_kernel(
    const unsigned short* __restrict__ ctx, const unsigned short* __restrict__ WoT,
    const float* __restrict__ bo, float* __restrict__ out) {
  __shared__ __align__(16) unsigned short smem[24576];  // 48 KB: 2x(As+Bs)
  const int lin = blockIdx.x + 8 * blockIdx.y;
  const int nlin = (lin & 7) * 64 + (lin >> 3);   // XCD chunk remap
  const int m0 = (nlin >> 3) * 64, n0 = (nlin & 7) * 128;
  const int t = threadIdx.x, l = t & 63, w = t >> 6;
  const int wm = w >> 1, wn = w & 1;
  const int lm = l & 15, lq = l >> 4;
  const int srow8 = t >> 3;
  const int fsw = ((t & 7) ^ ((t >> 3) & 7)) * 8;
  const int swm = lm & 7;

  auto stage = [&](int kt, int bsel) {
    const int kb = kt * 64;
    unsigned short* As = smem + bsel * 12288;
    unsigned short* Bs = As + 4096;
#pragma unroll
    for (int c = 0; c < 2; ++c)
      gload_lds16(&ctx[(size_t)(m0 + 32 * c + srow8) * D + kb + fsw],
                  &As[(32 * c + 8 * w) * 64]);
#pragma unroll
    for (int c = 0; c < 4; ++c)
      gload_lds16(&WoT[(size_t)(n0 + 32 * c + srow8) * D + kb + fsw],
                  &Bs[(32 * c + 8 * w) * 64]);
  };

  f32x4 acc[2][4] = {};
  stage(0, 0);
  __syncthreads();
  for (int kt = 0; kt < D / 64; ++kt) {
    const int cur = kt & 1;
    if (kt + 1 < D / 64) stage(kt + 1, cur ^ 1);
    const unsigned short* As = smem + cur * 12288;
    const unsigned short* Bs = As + 4096;
#pragma unroll
    for (int kk = 0; kk < 2; ++kk) {
      bf16x8 af[2], bf[4];
#pragma unroll
      for (int i = 0; i < 2; ++i)
        af[i] = *(const bf16x8*)&As[(32 * wm + 16 * i + lm) * 64 + ((kk * 4 + lq) ^ swm) * 8];
#pragma unroll
      for (int j = 0; j < 4; ++j)
        bf[j] = *(const bf16x8*)&Bs[(64 * wn + 16 * j + lm) * 64 + ((kk * 4 + lq) ^ swm) * 8];
#pragma unroll
      for (int i = 0; i < 2; ++i)
#pragma unroll
        for (int j = 0; j < 4; ++j)
          acc[i][j] = __builtin_amdgcn_mfma_f32_16x16x32_bf16(af[i], bf[j], acc[i][j], 0, 0, 0);
    }
    __syncthreads();
  }
#pragma unroll
  for (int i = 0; i < 2; ++i)
#pragma unroll
    for (int j = 0; j < 4; ++j)
#pragma unroll
      for (int r = 0; r < 4; ++r) {
        int grow = m0 + 32 * wm + 16 * i + lq * 4 + r;
        int gcol = n0 + 64 * wn + 16 * j + lm;
        out[(size_t)grow * D + gcol] = acc[i][j][r] + bo[gcol];
      }
}

extern "C" void kernel_launch(void* const* d_in, const int* in_sizes, int n_in,
                              void* d_out, int out_size, void* d_ws, size_t ws_size,
                              hipStream_t stream) {
  const float* x    = (const float*)d_in[0];
  const float* subj = (const float*)d_in[1];
  const unsigned char* mask = (const unsigned char*)d_in[2];
  const float* Wq = (const float*)d_in[3];
  const float* Wk = (const float*)d_in[4];
  const float* Wv = (const float*)d_in[5];
  const float* Wo = (const float*)d_in[6];
  const float* bo = (const float*)d_in[7];
  const float* Wsq = (const float*)d_in[8];
  const float* bsq = (const float*)d_in[9];
  const float* Wsk = (const float*)d_in[10];
  const float* bsk = (const float*)d_in[11];
  float* out = (float*)d_out;
  char* ws = (char*)d_ws;

  // workspace layout (bytes)
  unsigned short* xb  = (unsigned short*)(ws);                    // 8 MB
  unsigned short* WT4 = (unsigned short*)(ws + (8ull  << 20));    // 8 MB
  unsigned short* qk  = (unsigned short*)(ws + (16ull << 20));    // 16 MB (q,k)
  unsigned short* ctx = (unsigned short*)(ws + (32ull << 20));    // 8 MB
  unsigned short* vT  = (unsigned short*)(ws + (40ull << 20));    // 8 MB
  float* sq = (float*)(ws + (48ull << 20));                       // 8 KB
  float* sk = sq + B * D;

  hipLaunchKernelGGL(prep_kernel, dim3(3088), dim3(256), 0, stream,
                     Wq, Wk, Wv, Wo, x, subj, Wsq, bsq, Wsk, bsk, WT4, xb, sq, sk);
  hipLaunchKernelGGL(proj_kernel, dim3(8, 64, 1), dim3(256), 0, stream,
                     xb, WT4, sq, sk, qk, vT);
  hipLaunchKernelGGL(attn_kernel, dim3(512), dim3(512), 0, stream,
                     qk, qk + (size_t)M * D, vT, mask, ctx);
  hipLaunchKernelGGL(outgemm_kernel, dim3(8, 64, 1), dim3(256), 0, stream, ctx,
                     WT4 + 3ull * D * D, bo, out);
}